// Round 11
// baseline (105.544 us; speedup 1.0000x reference)
//
#include <hip/hip_runtime.h>
#include <math.h>

#define DEV static __device__ __forceinline__

typedef __bf16 bf16_t;
typedef __bf16 bf16x8 __attribute__((ext_vector_type(8)));
typedef float f32x4 __attribute__((ext_vector_type(4)));

#define MFMA16(a,b,c) __builtin_amdgcn_mfma_f32_16x16x32_bf16(a,b,c,0,0,0)

// ---------- fast transcendentals ----------
DEV float frcp(float x){ return __builtin_amdgcn_rcpf(x); }
DEV float softplus_fast(float x){
  return fmaxf(x, 0.f) + __logf(1.f + __expf(-fabsf(x)));
}
DEV float tanh_fast(float z){
  float e2 = __expf(2.f * z);
  return (e2 - 1.f) * frcp(e2 + 1.f);
}
DEV float gelu_fast(float v){
  float u = 0.7978845608028654f * fmaf(0.044715f * v, v * v, v);
  u = fminf(fmaxf(u, -15.f), 15.f);
  return 0.5f * v * (1.f + tanh_fast(u));
}

DEV void gl_lds16(const void* g, void* l) {
  __builtin_amdgcn_global_load_lds((const __attribute__((address_space(1))) void*)g,
                                   (__attribute__((address_space(3))) void*)l, 16, 0, 0);
}

DEV float waveReduceSum(float v){
  #pragma unroll
  for (int o = 32; o > 0; o >>= 1) v += __shfl_xor(v, o, 64);
  return v;
}
DEV float blockReduceSum(float v, float* sh){
  v = waveReduceSum(v);
  int w = threadIdx.x >> 6;
  int nw = blockDim.x >> 6;
  __syncthreads();
  if ((threadIdx.x & 63) == 0) sh[w] = v;
  __syncthreads();
  float r = sh[0];
  for (int i = 1; i < nw; i++) r += sh[i];
  return r;
}

// ---------------- prep: LN1 (blocks 0..2047) + weight conversions (rest) ----------------
__global__ __launch_bounds__(256) void prep(
    const float* __restrict__ xin,
    const float* __restrict__ g, const float* __restrict__ b,
    const float* __restrict__ Wq, const float* __restrict__ Wk,
    const float* __restrict__ Wv, const float* __restrict__ Wo,
    const float* __restrict__ W1, const float* __restrict__ W2,
    bf16_t* __restrict__ y, float* __restrict__ ty,
    bf16_t* __restrict__ Wqkvb, bf16_t* __restrict__ Wob,
    bf16_t* __restrict__ W1b, bf16_t* __restrict__ W2b,
    float* __restrict__ wqkv0, float* __restrict__ wo0,
    float* __restrict__ w10, float* __restrict__ w20)
{
  int t = threadIdx.x;
  if (blockIdx.x < 2048) {
    __shared__ float sh[8];
    int row = blockIdx.x;
    const float* xr = xin + (long)row * 513 + 1;
    float a0 = xr[t], a1 = xr[t + 256];
    float s  = blockReduceSum(a0 + a1, sh);
    float s2 = blockReduceSum(a0 * a0 + a1 * a1, sh);
    float mu = s * (1.f / 512.f);
    float var = s2 * (1.f / 512.f) - mu * mu;
    float inv = rsqrtf(var + 1e-5f);
    float y0 = (a0 - mu) * inv * g[t] + b[t];
    float y1v = (a1 - mu) * inv * g[t + 256] + b[t + 256];
    float q = blockReduceSum(y0 * y0 + y1v * y1v, sh);
    bf16_t* yr = y + (long)row * 512;
    yr[t] = (bf16_t)y0;
    yr[t + 256] = (bf16_t)y1v;
    if (t == 0) ty[row] = sqrtf(q + 1.f);
    return;
  }
  long i = (long)(blockIdx.x - 2048) * 256 + t;
  if (i < 786432) {                       // Wqkv spatial [1536][512]
    long r = i >> 9; int c = (int)(i & 511);
    const float* src = (r < 512) ? Wq + r * 513 : (r < 1024) ? Wk + (r - 512) * 513 : Wv + (r - 1024) * 513;
    Wqkvb[i] = (bf16_t)src[c + 1];
  } else if (i < 1048576) {               // Wo spatial [512][512]
    long j = i - 786432;
    long r = j >> 9; int c = (int)(j & 511);
    Wob[j] = (bf16_t)Wo[r * 513 + c + 1];
  } else if (i < 2097152) {               // W1 spatial [2048][512]
    long j = i - 1048576;
    long r = j >> 9; int c = (int)(j & 511);
    W1b[j] = (bf16_t)W1[r * 513 + c + 1];
  } else if (i < 3145728) {               // W2 spatial [512][2048]
    long j = i - 2097152;
    long r = j >> 11; int c = (int)(j & 2047);
    W2b[j] = (bf16_t)W2[r * 2049 + c + 1];
  } else if (i < 3150336) {               // time columns (fp32)
    int j = (int)(i - 3145728);
    if (j < 1536) {
      wqkv0[j] = (j < 512) ? Wq[(long)j * 513] : (j < 1024) ? Wk[(long)(j - 512) * 513] : Wv[(long)(j - 1024) * 513];
    } else if (j < 2048) wo0[j - 1536] = Wo[(long)(j - 1536) * 513];
    else if (j < 4096)  w10[j - 2048] = W1[(long)(j - 2048) * 513];
    else                w20[j - 4096] = W2[(long)(j - 4096) * 2049];
  }
}

// ---------------- residual + rank-1(Wo time) + LN2 -> outs, y2b, ty2 ----------------
__global__ __launch_bounds__(256) void res_ln(
    const float* __restrict__ woA, const float* __restrict__ woB,
    const float* __restrict__ ch2, const float* __restrict__ wo0,
    const float* __restrict__ xin,
    const float* __restrict__ g, const float* __restrict__ b,
    float* __restrict__ outs,
    bf16_t* __restrict__ y, float* __restrict__ ty)
{
  __shared__ float sh[8];
  int row = blockIdx.x;
  int t = threadIdx.x;
  const float* c = ch2 + (long)row * 8;
  float cs = ((c[0] + c[1]) + (c[2] + c[3])) + ((c[4] + c[5]) + (c[6] + c[7]));
  float tattn = sqrtf(fmaxf(cs - 7.f, 1e-8f));
  long i0 = (long)row * 512 + t, i1 = i0 + 256;
  float a0 = woA[i0] + woB[i0] + tattn * wo0[t]       + xin[(long)row * 513 + 1 + t];
  float a1 = woA[i1] + woB[i1] + tattn * wo0[t + 256] + xin[(long)row * 513 + 1 + t + 256];
  outs[i0] = a0;
  outs[i1] = a1;
  float s  = blockReduceSum(a0 + a1, sh);
  float s2 = blockReduceSum(a0 * a0 + a1 * a1, sh);
  float mu = s * (1.f / 512.f);
  float var = s2 * (1.f / 512.f) - mu * mu;
  float inv = rsqrtf(var + 1e-5f);
  float y0 = (a0 - mu) * inv * g[t] + b[t];
  float y1v = (a1 - mu) * inv * g[t + 256] + b[t + 256];
  float q = blockReduceSum(y0 * y0 + y1v * y1v, sh);
  bf16_t* yr = y + (long)row * 512;
  yr[t] = (bf16_t)y0;
  yr[t + 256] = (bf16_t)y1v;
  if (t == 0) ty[row] = sqrtf(q + 1.f);
}

// ---------------- final: th2p-sum + residual(4 partials) + rank-1 + add_time ----------------
__global__ __launch_bounds__(256) void final_k(
    const float* __restrict__ hA, const float* __restrict__ hB,
    const float* __restrict__ hC, const float* __restrict__ hD,
    const float* __restrict__ th2p, const float* __restrict__ w20,
    const float* __restrict__ outs,
    float* __restrict__ out)
{
  __shared__ float sh[8];
  int row = blockIdx.x;
  int t = threadIdx.x;
  float p = (t < 32) ? th2p[(long)t * 2048 + row] : 0.f;
  float hn = blockReduceSum(p, sh);
  float th = sqrtf(hn + 1.f);
  long i0 = (long)row * 512 + t, i1 = i0 + 256;
  float o0 = (hA[i0] + hB[i0]) + (hC[i0] + hD[i0]) + th * w20[t]       + outs[i0];
  float o1 = (hA[i1] + hB[i1]) + (hC[i1] + hD[i1]) + th * w20[t + 256] + outs[i1];
  float q = blockReduceSum(o0 * o0 + o1 * o1, sh);
  float* yr = out + (long)row * 513;
  yr[1 + t] = o0;
  yr[1 + t + 256] = o1;
  if (t == 0) yr[0] = sqrtf(q + 1.f);
}

// ---------------- vtan_tr: v_tan + transpose (V third of qkvsb only) ----------------
__global__ __launch_bounds__(256) void vtan_tr(
    const bf16_t* __restrict__ qkvsb, bf16_t* __restrict__ VTt)
{
  __shared__ bf16_t tile[64 * 72];
  int z = blockIdx.y, b = z >> 3, h = z & 7;
  int n0 = blockIdx.x * 64;
  int t = threadIdx.x;
  int r = t >> 2, c4 = t & 3;
  const bf16_t* vb = qkvsb + ((long)(b * 1024 + n0 + r) * 1536 + 1024 + h * 64 + c4 * 16);
  bf16x8 v0 = *(const bf16x8*)vb;
  bf16x8 v1 = *(const bf16x8*)(vb + 8);
  float ss = 0.f;
  #pragma unroll
  for (int e = 0; e < 8; e++) {
    float f0 = (float)v0[e], f1 = (float)v1[e];
    ss = fmaf(f0, f0, fmaf(f1, f1, ss));
  }
  ss += __shfl_xor(ss, 1, 64);
  ss += __shfl_xor(ss, 2, 64);
  float vT = sqrtf(1.f + ss);
  float sn0 = sqrtf(ss);
  float coef = __logf(vT + sn0) * frcp(fmaxf(sn0, 1e-8f));
  #pragma unroll
  for (int e = 0; e < 8; e++) {
    tile[(c4 * 16 + e) * 72 + r]     = (bf16_t)(coef * (float)v0[e]);
    tile[(c4 * 16 + 8 + e) * 72 + r] = (bf16_t)(coef * (float)v1[e]);
  }
  __syncthreads();
  int d = t >> 2, cc = (t & 3) * 16;
  bf16x8 o0 = *(const bf16x8*)&tile[d * 72 + cc];
  bf16x8 o1 = *(const bf16x8*)&tile[d * 72 + cc + 8];
  bf16_t* dst = VTt + (long)z * 64 * 1024 + (long)d * 1024 + n0 + cc;
  *(bf16x8*)dst = o0;
  *(bf16x8*)(dst + 8) = o1;
}

// ---------------- fused attention + expmap merge (XOR-swizzled LDS) ----------------
__global__ __launch_bounds__(256) void attn_fused(
    const bf16_t* __restrict__ qkvsb,   // [2048][1536]
    const bf16_t* __restrict__ VTt,     // [16][64][1024]
    const float* __restrict__ qt, const float* __restrict__ kt,
    const float* __restrict__ Bi,
    bf16_t* __restrict__ attnb,         // [2048][512]
    float* __restrict__ ch2,            // [2048][8]
    const float* __restrict__ lam_p, const float* __restrict__ tau_p,
    const float* __restrict__ temp_p)
{
  __shared__ bf16_t Ks[64 * 64];
  __shared__ bf16_t Vs[64 * 64];
  __shared__ bf16_t Ps[32 * 72];
  __shared__ float ot[32 * 65];
  __shared__ float sh_qt[32], sh_Bc[32], sh_kt[64], rs[32];

  const int t = threadIdx.x;
  const int w = t >> 6;
  const int lane = t & 63;
  const int lm = lane & 15, lh = lane >> 4;
  const int z = blockIdx.y, b = z >> 3, h = z & 7;
  const int n0 = blockIdx.x * 32;
  const int sb = (((lane & 7) ^ (lane >> 3)) << 4);
  const int r8 = lane >> 3;

  float lam = softplus_fast(lam_p[0]);
  float tau = softplus_fast(tau_p[0]);
  float invT = frcp(temp_p[0]);
  float A1 = -lam * invT, A2 = -tau * invT;
  float A2h = 0.5f * A2, K0 = A2 * 0.048750465f;

  if (t < 32) {
    sh_qt[t] = qt[z * 1024 + n0 + t];
    sh_Bc[t] = Bi[z * 1024 + n0 + t] - 0.1f;
    rs[t] = 0.f;
  }

  // stage Q (32x64, swizzled) then preload frags
  const bf16_t* qbase = qkvsb + ((long)(b * 1024 + n0) * 1536 + h * 64);
  gl_lds16((const char*)(qbase + (long)(w * 8 + r8) * 1536) + sb, (char*)Ks + w * 1024);
  __syncthreads();
  bf16x8 qf[2][2];
  #pragma unroll
  for (int i = 0; i < 2; i++)
    #pragma unroll
    for (int kk = 0; kk < 2; kk++)
      qf[i][kk] = *(const bf16x8*)&Ks[(i * 16 + lm) * 64 + (((kk * 4 + lh) ^ (lm & 7)) << 3)];

  f32x4 oacc[2] = {};
  float racc[2][4] = {};

  const bf16_t* kbase = qkvsb + ((long)b * 1024 * 1536 + 512 + h * 64);
  const bf16_t* vbase = VTt + (long)z * 64 * 1024;
  const int sl0 = ((lh) ^ (lm & 7)) << 3;
  const int sl1 = ((4 + lh) ^ (lm & 7)) << 3;

  for (int kv = 0; kv < 16; kv++) {
    __syncthreads();
    {
      const bf16_t* kb = kbase + (long)(kv * 64) * 1536;
      gl_lds16((const char*)(kb + (long)(w * 16 + r8) * 1536) + sb,     (char*)Ks + (w * 2) * 1024);
      gl_lds16((const char*)(kb + (long)(w * 16 + 8 + r8) * 1536) + sb, (char*)Ks + (w * 2 + 1) * 1024);
      const bf16_t* vb = vbase + kv * 64;
      gl_lds16((const char*)(vb + (long)(w * 16 + r8) * 1024) + sb,     (char*)Vs + (w * 2) * 1024);
      gl_lds16((const char*)(vb + (long)(w * 16 + 8 + r8) * 1024) + sb, (char*)Vs + (w * 2 + 1) * 1024);
    }
    if (t < 64) sh_kt[t] = kt[z * 1024 + kv * 64 + t];
    __syncthreads();

    f32x4 sacc[2] = {};
    bf16x8 kf0 = *(const bf16x8*)&Ks[(w * 16 + lm) * 64 + sl0];
    bf16x8 kf1 = *(const bf16x8*)&Ks[(w * 16 + lm) * 64 + sl1];
    sacc[0] = MFMA16(qf[0][0], kf0, sacc[0]);
    sacc[0] = MFMA16(qf[0][1], kf1, sacc[0]);
    sacc[1] = MFMA16(qf[1][0], kf0, sacc[1]);
    sacc[1] = MFMA16(qf[1][1], kf1, sacc[1]);

    float ktv = sh_kt[w * 16 + lm];
    #pragma unroll
    for (int i = 0; i < 2; i++) {
      #pragma unroll
      for (int q = 0; q < 4; q++) {
        int r = i * 16 + lh * 4 + q;
        float qtv = sh_qt[r], Bc = sh_Bc[r];
        float nOQ = fmaf(qtv, qtv, -1.f);
        float inner = fmaf(-qtv, ktv, sacc[i][q]);
        float nQK = fmaxf(fmaf(inner, inner, -1.f), 0.f);
        float ri = __builtin_amdgcn_rsqf(fmaf(nQK, nOQ, 2.5e-5f));
        float zr = fmaf(inner, qtv, ktv) * ri;
        float Zc = fminf(fmaxf(-zr, -1.f), 1.f);
        float xx = fmaxf(-inner, 1.001f);
        float u = fmaf(__log2f(xx), 0.01732868f, 0.01732868f);
        float p = fminf(u * u, 0.09f);
        float H = p * fmaf(p, -6.584f, 3.5556f);
        float a = Zc + Bc;
        float a2 = a * a;
        float lc = a2 * fmaf(a2, fmaf(a2, 0.00034722f, -0.0052083f), 0.125f);
        float lgt = fmaf(A1, H, fmaf(A2, lc, fmaf(A2h, a, K0)));
        float e = __expf(lgt);
        Ps[r * 72 + w * 16 + lm] = (bf16_t)e;
        racc[i][q] += e;
      }
    }
    __syncthreads();

    bf16x8 va0 = *(const bf16x8*)&Vs[(w * 16 + lm) * 64 + sl0];
    bf16x8 va1 = *(const bf16x8*)&Vs[(w * 16 + lm) * 64 + sl1];
    bf16x8 pb00 = *(const bf16x8*)&Ps[lm * 72 + lh * 8];
    bf16x8 pb01 = *(const bf16x8*)&Ps[lm * 72 + 32 + lh * 8];
    bf16x8 pb10 = *(const bf16x8*)&Ps[(16 + lm) * 72 + lh * 8];
    bf16x8 pb11 = *(const bf16x8*)&Ps[(16 + lm) * 72 + 32 + lh * 8];
    oacc[0] = MFMA16(va0, pb00, oacc[0]);
    oacc[0] = MFMA16(va1, pb01, oacc[0]);
    oacc[1] = MFMA16(va0, pb10, oacc[1]);
    oacc[1] = MFMA16(va1, pb11, oacc[1]);
  }

  #pragma unroll
  for (int i = 0; i < 2; i++)
    #pragma unroll
    for (int q = 0; q < 4; q++) {
      float v = racc[i][q];
      v += __shfl_xor(v, 1, 64);
      v += __shfl_xor(v, 2, 64);
      v += __shfl_xor(v, 4, 64);
      v += __shfl_xor(v, 8, 64);
      if (lm == 0) atomicAdd(&rs[i * 16 + lh * 4 + q], v);
    }

  #pragma unroll
  for (int j = 0; j < 2; j++)
    #pragma unroll
    for (int q = 0; q < 4; q++)
      ot[(j * 16 + lm) * 65 + w * 16 + lh * 4 + q] = oacc[j][q];
  __syncthreads();

  int r = t >> 3, c0 = (t & 7) * 8;
  float inv = frcp(rs[r] * (1.f + 1e-8f));
  float v[8];
  float ss = 0.f;
  #pragma unroll
  for (int e = 0; e < 8; e++) {
    v[e] = ot[r * 65 + c0 + e] * inv;
    ss = fmaf(v[e], v[e], ss);
  }
  ss += __shfl_xor(ss, 1, 64);
  ss += __shfl_xor(ss, 2, 64);
  ss += __shfl_xor(ss, 4, 64);
  float nn = fmaxf(sqrtf(ss), 1e-8f);
  float e_ = __expf(nn), ei = frcp(e_);
  float coef = 0.5f * (e_ - ei) * frcp(nn);
  bf16x8 ov;
  #pragma unroll
  for (int e = 0; e < 8; e++) ov[e] = (bf16_t)(coef * v[e]);
  *(bf16x8*)(attnb + (long)(b * 1024 + n0 + r) * 512 + h * 64 + c0) = ov;
  if (c0 == 0) {
    float ch = 0.5f * (e_ + ei);
    ch2[(long)(b * 1024 + n0 + r) * 8 + h] = ch * ch;
  }
}

// ============ bf16-out GEMM, 128x128 block, 4 waves of 64x64, BK=64, swizzled ============
// ACTF: 0 = GELU | 2 = plain.  STATS: 0 none | 1 qt/kt/Bi (QKV) | 2 row ||.||^2 partials (F1)
template<int ACTF, int STATS>
DEV void gemm_rep_body(
    const bf16_t* __restrict__ Ag, int lda,
    const bf16_t* __restrict__ Bg, int ldb,
    bf16_t* __restrict__ Cg, int ldc, int K,
    const float* __restrict__ trow, const float* __restrict__ w0,
    float* __restrict__ s0, float* __restrict__ s1, float* __restrict__ s2,
    const float* __restrict__ beta_p)
{
  __shared__ char smem[32768];          // k-loop: As 16K | Bs 16K ; epilogue: rep 32K
  __shared__ float sh_t[128];
  bf16_t* As = (bf16_t*)smem;           // [128][64]
  bf16_t* Bs = (bf16_t*)(smem + 16384); // [128][64]
  const int t = threadIdx.x;
  const int wid = t >> 6, lane = t & 63;
  const int lm = lane & 15, lh = lane >> 4;
  const int bm = blockIdx.x * 128;
  const int bn = blockIdx.y * 128;
  const int wm = (wid >> 1) * 64;
  const int wn = (wid & 1) * 64;
  const int sb = (((lane & 7) ^ (lane >> 3)) << 4);
  const int r8 = lane >> 3;
  f32x4 acc[4][4] = {};

  if (t < 128) sh_t[t] = trow[bm + t];
  float w0c[4];
  #pragma unroll
  for (int j = 0; j < 4; j++) w0c[j] = w0[bn + wn + j * 16 + lm];

  for (int kk = 0; kk < K; kk += 64) {
    __syncthreads();
    #pragma unroll
    for (int r = 0; r < 4; r++) {
      int chunk = wid * 4 + r;
      gl_lds16((const char*)(Ag + (long)(bm + chunk * 8 + r8) * lda + kk) + sb,
               smem + chunk * 1024);
      gl_lds16((const char*)(Bg + (long)(bn + chunk * 8 + r8) * ldb + kk) + sb,
               smem + 16384 + chunk * 1024);
    }
    __syncthreads();
    #pragma unroll
    for (int k2 = 0; k2 < 2; k2++) {
      const int sl = (((k2 * 4 + lh) ^ (lm & 7)) << 3);
      bf16x8 af[4], bfr[4];
      #pragma unroll
      for (int i = 0; i < 4; i++) af[i] = *(const bf16x8*)&As[(wm + i * 16 + lm) * 64 + sl];
      #pragma unroll
      for (int j = 0; j < 4; j++) bfr[j] = *(const bf16x8*)&Bs[(wn + j * 16 + lm) * 64 + sl];
      #pragma unroll
      for (int i = 0; i < 4; i++)
        #pragma unroll
        for (int j = 0; j < 4; j++)
          acc[i][j] = MFMA16(af[i], bfr[j], acc[i][j]);
    }
  }

  __syncthreads();                       // staging dead; reuse as rep[128][128]
  bf16_t* rep = (bf16_t*)smem;
  #pragma unroll
  for (int i = 0; i < 4; i++) {
    #pragma unroll
    for (int q = 0; q < 4; q++) {
      int r = wm + i * 16 + lh * 4 + q;
      #pragma unroll
      for (int j = 0; j < 4; j++) {
        float v = acc[i][j][q] + sh_t[r] * w0c[j];
        rep[r * 128 + wn + j * 16 + lm] = (bf16_t)(ACTF == 0 ? gelu_fast(v) : v);
      }
    }
  }
  __syncthreads();

  // 8 rounds: coalesced 16B LDS read -> coalesced 16B global store
  #pragma unroll
  for (int rd = 0; rd < 8; rd++) {
    int off = rd * 4096 + t * 16;
    int lr = off >> 8;                  // 256 B/row
    int lc = (off & 255) >> 1;
    bf16x8 vv = *(const bf16x8*)(smem + off);
    *(bf16x8*)(Cg + (long)(bm + lr) * ldc + bn + lc) = vv;
  }

  if constexpr (STATS != 0) {
    // thread t: row rr = t>>1, 64-col half = t&1 (one head / one slot)
    int rr = t >> 1, half = t & 1;
    const bf16_t* rp = rep + rr * 128 + half * 64;
    float s = 0.f;
    #pragma unroll
    for (int c = 0; c < 8; c++) {
      int cc = c ^ (rr & 7);            // permuted order: spread banks across rows
      bf16x8 vv = *(const bf16x8*)(rp + cc * 8);
      #pragma unroll
      for (int e = 0; e < 8; e++) { float f = (float)vv[e]; s = fmaf(f, f, s); }
    }
    if constexpr (STATS == 2) {
      int slot = (bn >> 6) + half;
      s0[(long)slot * 2048 + bm + rr] = s;                 // ||h_row||^2 partial (64 cols)
    } else {
      int bnh = (bn >> 6) + half;                          // 0..23: q heads, k heads, v heads
      if (bnh < 16) {
        int grow = bm + rr, bloc = grow >> 10, n = grow & 1023;
        if (bnh < 8) {
          int zz = bloc * 8 + bnh;
          float qT = sqrtf(1.f + s);
          s0[zz * 1024 + n] = qT;
          float beta = softplus_fast(beta_p[0]);
          float xq = fmaxf(qT, 1.001f);
          float sh_ = sqrtf(fmaxf(xq * xq - 1.f, 0.f));
          float rr0 = beta * frcp(sh_);
          s2[zz * 1024 + n] = sqrtf(fmaxf(1.f - rr0 * rr0, 0.f) + 1e-8f);
        } else {
          int zz = bloc * 8 + (bnh - 8);
          s1[zz * 1024 + n] = sqrtf(1.f + s);
        }
      }
    }
  }
}

// ---------------- fp32-out GEMM, 128x64 block, 4 waves of 64x32, BK=64, K-range ----------------
DEV void gemm_f32_body(
    const bf16_t* __restrict__ Ag, int lda,
    const bf16_t* __restrict__ Bg, int ldb,
    float* __restrict__ Cg, int ldc,
    int k0, int k1)
{
  __shared__ bf16_t As[128 * 64];
  __shared__ bf16_t Bs[64 * 64];
  const int t = threadIdx.x;
  const int wid = t >> 6, lane = t & 63;
  const int lm = lane & 15, lh = lane >> 4;
  const int bm = blockIdx.x * 128;
  const int bn = blockIdx.y * 64;
  const int wm = (wid >> 1) * 64;
  const int wn = (wid & 1) * 32;
  const int sb = (((lane & 7) ^ (lane >> 3)) << 4);
  const int r8 = lane >> 3;
  f32x4 acc[4][2] = {};

  for (int kk = k0; kk < k1; kk += 64) {
    __syncthreads();
    #pragma unroll
    for (int r = 0; r < 4; r++) {
      int chunk = wid * 4 + r;
      gl_lds16((const char*)(Ag + (long)(bm + chunk * 8 + r8) * lda + kk) + sb,
               (char*)As + chunk * 1024);
    }
    #pragma unroll
    for (int r = 0; r < 2; r++) {
      int chunk = wid * 2 + r;
      gl_lds16((const char*)(Bg + (long)(bn + chunk * 8 + r8) * ldb + kk) + sb,
               (char*)Bs + chunk * 1024);
    }
    __syncthreads();
    #pragma unroll
    for (int k2 = 0; k2 < 2; k2++) {
      const int sl = (((k2 * 4 + lh) ^ (lm & 7)) << 3);
      bf16x8 af[4], bfr[2];
      #pragma unroll
      for (int i = 0; i < 4; i++) af[i] = *(const bf16x8*)&As[(wm + i * 16 + lm) * 64 + sl];
      #pragma unroll
      for (int j = 0; j < 2; j++) bfr[j] = *(const bf16x8*)&Bs[(wn + j * 16 + lm) * 64 + sl];
      #pragma unroll
      for (int i = 0; i < 4; i++)
        #pragma unroll
        for (int j = 0; j < 2; j++)
          acc[i][j] = MFMA16(af[i], bfr[j], acc[i][j]);
    }
  }

  #pragma unroll
  for (int i = 0; i < 4; i++) {
    #pragma unroll
    for (int q = 0; q < 4; q++) {
      long row = bm + wm + i * 16 + lh * 4 + q;
      #pragma unroll
      for (int j = 0; j < 2; j++)
        Cg[row * ldc + bn + wn + j * 16 + lm] = acc[i][j][q];
    }
  }
}

// ---- named wrappers ----
__global__ __launch_bounds__(256) void gemm_qkv(const bf16_t* A, int lda, const bf16_t* B, int ldb,
                                                bf16_t* C, int ldc, int K,
                                                const float* trow, const float* w0,
                                                float* qt, float* kt, float* Bi, const float* beta){
  gemm_rep_body<2, 1>(A, lda, B, ldb, C, ldc, K, trow, w0, qt, kt, Bi, beta);
}
__global__ __launch_bounds__(256) void gemm_f1(const bf16_t* A, int lda, const bf16_t* B, int ldb,
                                               bf16_t* C, int ldc, int K,
                                               const float* trow, const float* w0,
                                               float* th2p){
  gemm_rep_body<0, 2>(A, lda, B, ldb, C, ldc, K, trow, w0, th2p, nullptr, nullptr, nullptr);
}
__global__ __launch_bounds__(256) void gemm_wo(const bf16_t* A, int lda, const bf16_t* B, int ldb,
                                               float* C, int ldc, int K){
  int k0 = blockIdx.z * (K >> 1);
  gemm_f32_body(A, lda, B, ldb, C + (long)blockIdx.z * 2048 * ldc, ldc, k0, k0 + (K >> 1));
}
__global__ __launch_bounds__(256) void gemm_f2(const bf16_t* A, int lda, const bf16_t* B, int ldb,
                                               float* C, int ldc, int K){
  int k0 = blockIdx.z * (K >> 2);
  gemm_f32_body(A, lda, B, ldb, C + (long)blockIdx.z * 2048 * ldc, ldc, k0, k0 + (K >> 2));
}

extern "C" void kernel_launch(void* const* d_in, const int* in_sizes, int n_in,
                              void* d_out, int out_size, void* d_ws, size_t ws_size,
                              hipStream_t stream) {
  const float* x    = (const float*)d_in[0];
  const float* Wq   = (const float*)d_in[1];
  const float* Wk   = (const float*)d_in[2];
  const float* Wv   = (const float*)d_in[3];
  const float* Wo   = (const float*)d_in[4];
  const float* W1   = (const float*)d_in[5];
  const float* W2   = (const float*)d_in[6];
  const float* g1   = (const float*)d_in[7];
  const float* b1   = (const float*)d_in[8];
  const float* g2   = (const float*)d_in[9];
  const float* b2   = (const float*)d_in[10];
  const float* temp = (const float*)d_in[11];
  const float* beta = (const float*)d_in[12];
  const float* tau  = (const float*)d_in[13];
  const float* lam  = (const float*)d_in[14];

  char* W = (char*)d_ws;
  bf16_t* Wqkvb = (bf16_t*)(W + 0);          // [1536][512]
  bf16_t* Wob   = (bf16_t*)(W + 1572864);    // [512][512]
  bf16_t* W1b   = (bf16_t*)(W + 2097152);    // [2048][512]
  bf16_t* W2b   = (bf16_t*)(W + 4194304);    // [512][2048]
  float*  wqkv0 = (float*) (W + 6291456);    // [1536]
  float*  wo0   = (float*) (W + 6297600);    // [512]
  float*  w10   = (float*) (W + 6299648);    // [2048]
  float*  w20   = (float*) (W + 6307840);    // [512]
  bf16_t* y1b   = (bf16_t*)(W + 6309888);    // [2048][512]
  float*  ty1   = (float*) (W + 8407040);    // [2048]
  bf16_t* qkvsb = (bf16_t*)(W + 8415232);    // [2048][1536]
  float*  qt    = (float*) (W + 14706688);   // [16384]
  float*  kt    = (float*) (W + 14772224);
  float*  Bi    = (float*) (W + 14837760);
  bf16_t* VTt   = (bf16_t*)(W + 14903296);   // [16][64][1024]
  float*  ch2   = (float*) (W + 17000448);   // [2048][8]
  bf16_t* attnb = (bf16_t*)(W + 17065984);   // [2048][512]
  float*  tmpA  = (float*) (W + 19163136);   // [2048][512] x4 partials (contiguous)
  float*  outs  = (float*) (W + 35940352);   // [2048][512]
  bf16_t* y2b   = (bf16_t*)(W + 40134656);   // [2048][512]
  float*  ty2   = (float*) (W + 42231808);   // [2048]
  bf16_t* hb    = (bf16_t*)(W + 42240000);   // [2048][2048]
  float*  th2p  = (float*) (W + 50628608);   // [32][2048]
  float*  tmpB  = tmpA + 1048576;
  float*  tmpC  = tmpA + 2097152;
  float*  tmpD  = tmpA + 3145728;

  // 0. LN1 + weight conversions (fused)
  prep<<<14354, 256, 0, stream>>>(x, g1, b1, Wq, Wk, Wv, Wo, W1, W2,
                                  y1b, ty1, Wqkvb, Wob, W1b, W2b, wqkv0, wo0, w10, w20);

  // 1. QKV projection (K=512, 128x128 tiles) + rank-1 + q/k stats -> qkvsb, qt, kt, Bi
  gemm_qkv<<<dim3(16,12,1),256,0,stream>>>(y1b, 512, Wqkvb, 512, qkvsb, 1536, 512,
                                           ty1, wqkv0, qt, kt, Bi, beta);

  // 2. v_tan + transpose -> VTt
  vtan_tr<<<dim3(16,16,1),256,0,stream>>>(qkvsb, VTt);

  // 3. fused attention + expmap merge -> attnb + ch2
  attn_fused<<<dim3(32,16,1),256,0,stream>>>(qkvsb, VTt, qt, kt, Bi, attnb, ch2, lam, tau, temp);

  // 4. Wo projection (K=512, split 2, 128x64 tiles) -> tmpA/tmpB
  gemm_wo<<<dim3(16,8,2),256,0,stream>>>(attnb, 512, Wob, 512, tmpA, 512, 512);

  // 5. residual + rank-1(Wo time via ch2) + LN2 -> outs, y2b, ty2
  res_ln<<<2048, 256, 0, stream>>>(tmpA, tmpB, ch2, wo0, x, g2, b2, outs, y2b, ty2);

  // 6. FFN up (K=512, 128x128 tiles) + rank-1 + GELU + ||h||^2 partials -> hb, th2p
  gemm_f1<<<dim3(16,16,1),256,0,stream>>>(y2b, 512, W1b, 512, hb, 2048, 512, ty2, w10, th2p);

  // 7. FFN down (K=2048, split 4, 128x64 tiles) -> tmpA..D
  gemm_f2<<<dim3(16,8,4),256,0,stream>>>(hb, 2048, W2b, 2048, tmpA, 512, 2048);

  // 8. final: th from th2p + residual + rank-1(W2 time) + add_time -> d_out
  final_k<<<2048, 256, 0, stream>>>(tmpA, tmpB, tmpC, tmpD, th2p, w20, outs, (float*)d_out);
}

// Round 12
// 96.509 us; speedup vs baseline: 1.0936x; 1.0936x over previous
//
#include <hip/hip_runtime.h>
#include <math.h>

#define DEV static __device__ __forceinline__

typedef __bf16 bf16_t;
typedef __bf16 bf16x8 __attribute__((ext_vector_type(8)));
typedef float f32x4 __attribute__((ext_vector_type(4)));

#define MFMA16(a,b,c) __builtin_amdgcn_mfma_f32_16x16x32_bf16(a,b,c,0,0,0)

// ---------- fast transcendentals ----------
DEV float frcp(float x){ return __builtin_amdgcn_rcpf(x); }
DEV float softplus_fast(float x){
  return fmaxf(x, 0.f) + __logf(1.f + __expf(-fabsf(x)));
}
DEV float tanh_fast(float z){
  float e2 = __expf(2.f * z);
  return (e2 - 1.f) * frcp(e2 + 1.f);
}
DEV float gelu_fast(float v){
  float u = 0.7978845608028654f * fmaf(0.044715f * v, v * v, v);
  u = fminf(fmaxf(u, -15.f), 15.f);
  return 0.5f * v * (1.f + tanh_fast(u));
}

DEV void gl_lds16(const void* g, void* l) {
  __builtin_amdgcn_global_load_lds((const __attribute__((address_space(1))) void*)g,
                                   (__attribute__((address_space(3))) void*)l, 16, 0, 0);
}

DEV float waveReduceSum(float v){
  #pragma unroll
  for (int o = 32; o > 0; o >>= 1) v += __shfl_xor(v, o, 64);
  return v;
}
DEV float blockReduceSum(float v, float* sh){
  v = waveReduceSum(v);
  int w = threadIdx.x >> 6;
  int nw = blockDim.x >> 6;
  __syncthreads();
  if ((threadIdx.x & 63) == 0) sh[w] = v;
  __syncthreads();
  float r = sh[0];
  for (int i = 1; i < nw; i++) r += sh[i];
  return r;
}

// ---------------- prep: LN1 (blocks 0..2047) + weight conversions (rest) ----------------
__global__ __launch_bounds__(256) void prep(
    const float* __restrict__ xin,
    const float* __restrict__ g, const float* __restrict__ b,
    const float* __restrict__ Wq, const float* __restrict__ Wk,
    const float* __restrict__ Wv, const float* __restrict__ Wo,
    const float* __restrict__ W1, const float* __restrict__ W2,
    bf16_t* __restrict__ y, float* __restrict__ ty,
    bf16_t* __restrict__ Wqkvb, bf16_t* __restrict__ Wob,
    bf16_t* __restrict__ W1b, bf16_t* __restrict__ W2b,
    float* __restrict__ wqkv0, float* __restrict__ wo0,
    float* __restrict__ w10, float* __restrict__ w20)
{
  int t = threadIdx.x;
  if (blockIdx.x < 2048) {
    __shared__ float sh[8];
    int row = blockIdx.x;
    const float* xr = xin + (long)row * 513 + 1;
    float a0 = xr[t], a1 = xr[t + 256];
    float s  = blockReduceSum(a0 + a1, sh);
    float s2 = blockReduceSum(a0 * a0 + a1 * a1, sh);
    float mu = s * (1.f / 512.f);
    float var = s2 * (1.f / 512.f) - mu * mu;
    float inv = rsqrtf(var + 1e-5f);
    float y0 = (a0 - mu) * inv * g[t] + b[t];
    float y1v = (a1 - mu) * inv * g[t + 256] + b[t + 256];
    float q = blockReduceSum(y0 * y0 + y1v * y1v, sh);
    bf16_t* yr = y + (long)row * 512;
    yr[t] = (bf16_t)y0;
    yr[t + 256] = (bf16_t)y1v;
    if (t == 0) ty[row] = sqrtf(q + 1.f);
    return;
  }
  long i = (long)(blockIdx.x - 2048) * 256 + t;
  if (i < 786432) {                       // Wqkv spatial [1536][512]
    long r = i >> 9; int c = (int)(i & 511);
    const float* src = (r < 512) ? Wq + r * 513 : (r < 1024) ? Wk + (r - 512) * 513 : Wv + (r - 1024) * 513;
    Wqkvb[i] = (bf16_t)src[c + 1];
  } else if (i < 1048576) {               // Wo spatial [512][512]
    long j = i - 786432;
    long r = j >> 9; int c = (int)(j & 511);
    Wob[j] = (bf16_t)Wo[r * 513 + c + 1];
  } else if (i < 2097152) {               // W1 spatial [2048][512]
    long j = i - 1048576;
    long r = j >> 9; int c = (int)(j & 511);
    W1b[j] = (bf16_t)W1[r * 513 + c + 1];
  } else if (i < 3145728) {               // W2 spatial [512][2048]
    long j = i - 2097152;
    long r = j >> 11; int c = (int)(j & 2047);
    W2b[j] = (bf16_t)W2[r * 2049 + c + 1];
  } else if (i < 3150336) {               // time columns (fp32)
    int j = (int)(i - 3145728);
    if (j < 1536) {
      wqkv0[j] = (j < 512) ? Wq[(long)j * 513] : (j < 1024) ? Wk[(long)(j - 512) * 513] : Wv[(long)(j - 1024) * 513];
    } else if (j < 2048) wo0[j - 1536] = Wo[(long)(j - 1536) * 513];
    else if (j < 4096)  w10[j - 2048] = W1[(long)(j - 2048) * 513];
    else                w20[j - 4096] = W2[(long)(j - 4096) * 2049];
  }
}

// ---------------- residual + rank-1(Wo time) + LN2 -> outs, y2b, ty2 ----------------
__global__ __launch_bounds__(256) void res_ln(
    const float* __restrict__ woA, const float* __restrict__ woB,
    const float* __restrict__ ch2, const float* __restrict__ wo0,
    const float* __restrict__ xin,
    const float* __restrict__ g, const float* __restrict__ b,
    float* __restrict__ outs,
    bf16_t* __restrict__ y, float* __restrict__ ty)
{
  __shared__ float sh[8];
  int row = blockIdx.x;
  int t = threadIdx.x;
  const float* c = ch2 + (long)row * 8;
  float cs = ((c[0] + c[1]) + (c[2] + c[3])) + ((c[4] + c[5]) + (c[6] + c[7]));
  float tattn = sqrtf(fmaxf(cs - 7.f, 1e-8f));
  long i0 = (long)row * 512 + t, i1 = i0 + 256;
  float a0 = woA[i0] + woB[i0] + tattn * wo0[t]       + xin[(long)row * 513 + 1 + t];
  float a1 = woA[i1] + woB[i1] + tattn * wo0[t + 256] + xin[(long)row * 513 + 1 + t + 256];
  outs[i0] = a0;
  outs[i1] = a1;
  float s  = blockReduceSum(a0 + a1, sh);
  float s2 = blockReduceSum(a0 * a0 + a1 * a1, sh);
  float mu = s * (1.f / 512.f);
  float var = s2 * (1.f / 512.f) - mu * mu;
  float inv = rsqrtf(var + 1e-5f);
  float y0 = (a0 - mu) * inv * g[t] + b[t];
  float y1v = (a1 - mu) * inv * g[t + 256] + b[t + 256];
  float q = blockReduceSum(y0 * y0 + y1v * y1v, sh);
  bf16_t* yr = y + (long)row * 512;
  yr[t] = (bf16_t)y0;
  yr[t + 256] = (bf16_t)y1v;
  if (t == 0) ty[row] = sqrtf(q + 1.f);
}

// ---------------- final: th2p-sum + residual(4 partials) + rank-1 + add_time ----------------
__global__ __launch_bounds__(256) void final_k(
    const float* __restrict__ hA, const float* __restrict__ hB,
    const float* __restrict__ hC, const float* __restrict__ hD,
    const float* __restrict__ th2p, const float* __restrict__ w20,
    const float* __restrict__ outs,
    float* __restrict__ out)
{
  __shared__ float sh[8];
  int row = blockIdx.x;
  int t = threadIdx.x;
  float p = (t < 32) ? th2p[(long)t * 2048 + row] : 0.f;
  float hn = blockReduceSum(p, sh);
  float th = sqrtf(hn + 1.f);
  long i0 = (long)row * 512 + t, i1 = i0 + 256;
  float o0 = (hA[i0] + hB[i0]) + (hC[i0] + hD[i0]) + th * w20[t]       + outs[i0];
  float o1 = (hA[i1] + hB[i1]) + (hC[i1] + hD[i1]) + th * w20[t + 256] + outs[i1];
  float q = blockReduceSum(o0 * o0 + o1 * o1, sh);
  float* yr = out + (long)row * 513;
  yr[1 + t] = o0;
  yr[1 + t + 256] = o1;
  if (t == 0) yr[0] = sqrtf(q + 1.f);
}

// ---------------- fused attention + expmap merge (XOR-swizzled LDS) ----------------
__global__ __launch_bounds__(256) void attn_fused(
    const bf16_t* __restrict__ qkvsb,   // [2048][1536]
    const bf16_t* __restrict__ VTt,     // [16][64][1024]
    const float* __restrict__ qt, const float* __restrict__ kt,
    const float* __restrict__ Bi,
    bf16_t* __restrict__ attnb,         // [2048][512]
    float* __restrict__ ch2,            // [2048][8]
    const float* __restrict__ lam_p, const float* __restrict__ tau_p,
    const float* __restrict__ temp_p)
{
  __shared__ bf16_t Ks[64 * 64];
  __shared__ bf16_t Vs[64 * 64];
  __shared__ bf16_t Ps[32 * 72];
  __shared__ float ot[32 * 65];
  __shared__ float sh_qt[32], sh_Bc[32], sh_kt[64], rs[32];

  const int t = threadIdx.x;
  const int w = t >> 6;
  const int lane = t & 63;
  const int lm = lane & 15, lh = lane >> 4;
  const int z = blockIdx.y, b = z >> 3, h = z & 7;
  const int n0 = blockIdx.x * 32;
  const int sb = (((lane & 7) ^ (lane >> 3)) << 4);
  const int r8 = lane >> 3;

  float lam = softplus_fast(lam_p[0]);
  float tau = softplus_fast(tau_p[0]);
  float invT = frcp(temp_p[0]);
  float A1 = -lam * invT, A2 = -tau * invT;
  float A2h = 0.5f * A2, K0 = A2 * 0.048750465f;

  if (t < 32) {
    sh_qt[t] = qt[z * 1024 + n0 + t];
    sh_Bc[t] = Bi[z * 1024 + n0 + t] - 0.1f;
    rs[t] = 0.f;
  }

  // stage Q (32x64, swizzled) then preload frags
  const bf16_t* qbase = qkvsb + ((long)(b * 1024 + n0) * 1536 + h * 64);
  gl_lds16((const char*)(qbase + (long)(w * 8 + r8) * 1536) + sb, (char*)Ks + w * 1024);
  __syncthreads();
  bf16x8 qf[2][2];
  #pragma unroll
  for (int i = 0; i < 2; i++)
    #pragma unroll
    for (int kk = 0; kk < 2; kk++)
      qf[i][kk] = *(const bf16x8*)&Ks[(i * 16 + lm) * 64 + (((kk * 4 + lh) ^ (lm & 7)) << 3)];

  f32x4 oacc[2] = {};
  float racc[2][4] = {};

  const bf16_t* kbase = qkvsb + ((long)b * 1024 * 1536 + 512 + h * 64);
  const bf16_t* vbase = VTt + (long)z * 64 * 1024;
  const int sl0 = ((lh) ^ (lm & 7)) << 3;
  const int sl1 = ((4 + lh) ^ (lm & 7)) << 3;

  for (int kv = 0; kv < 16; kv++) {
    __syncthreads();
    {
      const bf16_t* kb = kbase + (long)(kv * 64) * 1536;
      gl_lds16((const char*)(kb + (long)(w * 16 + r8) * 1536) + sb,     (char*)Ks + (w * 2) * 1024);
      gl_lds16((const char*)(kb + (long)(w * 16 + 8 + r8) * 1536) + sb, (char*)Ks + (w * 2 + 1) * 1024);
      const bf16_t* vb = vbase + kv * 64;
      gl_lds16((const char*)(vb + (long)(w * 16 + r8) * 1024) + sb,     (char*)Vs + (w * 2) * 1024);
      gl_lds16((const char*)(vb + (long)(w * 16 + 8 + r8) * 1024) + sb, (char*)Vs + (w * 2 + 1) * 1024);
    }
    if (t < 64) sh_kt[t] = kt[z * 1024 + kv * 64 + t];
    __syncthreads();

    f32x4 sacc[2] = {};
    bf16x8 kf0 = *(const bf16x8*)&Ks[(w * 16 + lm) * 64 + sl0];
    bf16x8 kf1 = *(const bf16x8*)&Ks[(w * 16 + lm) * 64 + sl1];
    sacc[0] = MFMA16(qf[0][0], kf0, sacc[0]);
    sacc[0] = MFMA16(qf[0][1], kf1, sacc[0]);
    sacc[1] = MFMA16(qf[1][0], kf0, sacc[1]);
    sacc[1] = MFMA16(qf[1][1], kf1, sacc[1]);

    float ktv = sh_kt[w * 16 + lm];
    #pragma unroll
    for (int i = 0; i < 2; i++) {
      #pragma unroll
      for (int q = 0; q < 4; q++) {
        int r = i * 16 + lh * 4 + q;
        float qtv = sh_qt[r], Bc = sh_Bc[r];
        float nOQ = fmaf(qtv, qtv, -1.f);
        float inner = fmaf(-qtv, ktv, sacc[i][q]);
        float nQK = fmaxf(fmaf(inner, inner, -1.f), 0.f);
        float ri = __builtin_amdgcn_rsqf(fmaf(nQK, nOQ, 2.5e-5f));
        float zr = fmaf(inner, qtv, ktv) * ri;
        float Zc = fminf(fmaxf(-zr, -1.f), 1.f);
        float xx = fmaxf(-inner, 1.001f);
        float u = fmaf(__log2f(xx), 0.01732868f, 0.01732868f);
        float p = fminf(u * u, 0.09f);
        float H = p * fmaf(p, -6.584f, 3.5556f);
        float a = Zc + Bc;
        float a2 = a * a;
        float lc = a2 * fmaf(a2, fmaf(a2, 0.00034722f, -0.0052083f), 0.125f);
        float lgt = fmaf(A1, H, fmaf(A2, lc, fmaf(A2h, a, K0)));
        float e = __expf(lgt);
        Ps[r * 72 + w * 16 + lm] = (bf16_t)e;
        racc[i][q] += e;
      }
    }
    __syncthreads();

    bf16x8 va0 = *(const bf16x8*)&Vs[(w * 16 + lm) * 64 + sl0];
    bf16x8 va1 = *(const bf16x8*)&Vs[(w * 16 + lm) * 64 + sl1];
    bf16x8 pb00 = *(const bf16x8*)&Ps[lm * 72 + lh * 8];
    bf16x8 pb01 = *(const bf16x8*)&Ps[lm * 72 + 32 + lh * 8];
    bf16x8 pb10 = *(const bf16x8*)&Ps[(16 + lm) * 72 + lh * 8];
    bf16x8 pb11 = *(const bf16x8*)&Ps[(16 + lm) * 72 + 32 + lh * 8];
    oacc[0] = MFMA16(va0, pb00, oacc[0]);
    oacc[0] = MFMA16(va1, pb01, oacc[0]);
    oacc[1] = MFMA16(va0, pb10, oacc[1]);
    oacc[1] = MFMA16(va1, pb11, oacc[1]);
  }

  #pragma unroll
  for (int i = 0; i < 2; i++)
    #pragma unroll
    for (int q = 0; q < 4; q++) {
      float v = racc[i][q];
      v += __shfl_xor(v, 1, 64);
      v += __shfl_xor(v, 2, 64);
      v += __shfl_xor(v, 4, 64);
      v += __shfl_xor(v, 8, 64);
      if (lm == 0) atomicAdd(&rs[i * 16 + lh * 4 + q], v);
    }

  #pragma unroll
  for (int j = 0; j < 2; j++)
    #pragma unroll
    for (int q = 0; q < 4; q++)
      ot[(j * 16 + lm) * 65 + w * 16 + lh * 4 + q] = oacc[j][q];
  __syncthreads();

  int r = t >> 3, c0 = (t & 7) * 8;
  float inv = frcp(rs[r] * (1.f + 1e-8f));
  float v[8];
  float ss = 0.f;
  #pragma unroll
  for (int e = 0; e < 8; e++) {
    v[e] = ot[r * 65 + c0 + e] * inv;
    ss = fmaf(v[e], v[e], ss);
  }
  ss += __shfl_xor(ss, 1, 64);
  ss += __shfl_xor(ss, 2, 64);
  ss += __shfl_xor(ss, 4, 64);
  float nn = fmaxf(sqrtf(ss), 1e-8f);
  float e_ = __expf(nn), ei = frcp(e_);
  float coef = 0.5f * (e_ - ei) * frcp(nn);
  bf16x8 ov;
  #pragma unroll
  for (int e = 0; e < 8; e++) ov[e] = (bf16_t)(coef * v[e]);
  *(bf16x8*)(attnb + (long)(b * 1024 + n0 + r) * 512 + h * 64 + c0) = ov;
  if (c0 == 0) {
    float ch = 0.5f * (e_ + ei);
    ch2[(long)(b * 1024 + n0 + r) * 8 + h] = ch * ch;
  }
}

// ============ bf16-out GEMM, 128x64 tiles, BK=64, swizzled, rank-1 + stats + v_tan fusion ============
// ACTF: 0 = GELU | 2 = plain.  STATS: 0 none | 1 qkv (q/k stats, v->VTt) | 2 row ||.||^2 partials (F1)
template<int ACTF, int STATS>
DEV void gemm_rep_body(
    const bf16_t* __restrict__ Ag, int lda,
    const bf16_t* __restrict__ Bg, int ldb,
    bf16_t* __restrict__ Cg, int ldc, int K,
    const float* __restrict__ trow, const float* __restrict__ w0,
    float* __restrict__ s0, float* __restrict__ s1, float* __restrict__ s2,
    const float* __restrict__ beta_p,
    bf16_t* __restrict__ vtt)
{
  __shared__ char smem[24576];          // k-loop: As 16K | Bs 8K ; epilogue reuse
  __shared__ float sh_t[128];
  __shared__ float shc[128];
  bf16_t* As = (bf16_t*)smem;
  bf16_t* Bs = (bf16_t*)(smem + 16384);
  const int t = threadIdx.x;
  const int wid = t >> 6, lane = t & 63;
  const int lm = lane & 15, lh = lane >> 4;
  const int bm = blockIdx.x * 128;
  const int bn = blockIdx.y * 64;
  const int wm = (wid >> 1) * 64;
  const int wn = (wid & 1) * 32;
  const int sb = (((lane & 7) ^ (lane >> 3)) << 4);
  const int r8 = lane >> 3;
  f32x4 acc[4][2] = {};

  if (t < 128) sh_t[t] = trow[bm + t];
  float w0c[2] = { w0[bn + wn + lm], w0[bn + wn + 16 + lm] };

  for (int kk = 0; kk < K; kk += 64) {
    __syncthreads();
    #pragma unroll
    for (int r = 0; r < 4; r++) {
      int chunk = wid * 4 + r;
      gl_lds16((const char*)(Ag + (long)(bm + chunk * 8 + r8) * lda + kk) + sb,
               smem + chunk * 1024);
    }
    #pragma unroll
    for (int r = 0; r < 2; r++) {
      int chunk = wid * 2 + r;
      gl_lds16((const char*)(Bg + (long)(bn + chunk * 8 + r8) * ldb + kk) + sb,
               smem + 16384 + chunk * 1024);
    }
    __syncthreads();
    #pragma unroll
    for (int k2 = 0; k2 < 2; k2++) {
      const int sl = (((k2 * 4 + lh) ^ (lm & 7)) << 3);
      bf16x8 af[4], bfr[2];
      #pragma unroll
      for (int i = 0; i < 4; i++) af[i] = *(const bf16x8*)&As[(wm + i * 16 + lm) * 64 + sl];
      #pragma unroll
      for (int j = 0; j < 2; j++) bfr[j] = *(const bf16x8*)&Bs[(wn + j * 16 + lm) * 64 + sl];
      #pragma unroll
      for (int i = 0; i < 4; i++)
        #pragma unroll
        for (int j = 0; j < 2; j++)
          acc[i][j] = MFMA16(af[i], bfr[j], acc[i][j]);
    }
  }

  __syncthreads();                       // staging dead

  if (STATS == 1 && blockIdx.y >= 16) {
    // ---- v-tile path: v_tan + transpose fused; no qkvsb write ----
    bf16_t* repv = (bf16_t*)smem;        // [128][68] padded
    #pragma unroll
    for (int i = 0; i < 4; i++) {
      #pragma unroll
      for (int q = 0; q < 4; q++) {
        int r = wm + i * 16 + lh * 4 + q;
        #pragma unroll
        for (int j = 0; j < 2; j++) {
          float v = acc[i][j][q] + sh_t[r] * w0c[j];
          repv[r * 68 + wn + j * 16 + lm] = (bf16_t)v;
        }
      }
    }
    __syncthreads();
    // per-row ||v||^2 -> coef
    {
      int rr = t >> 1, half = t & 1;
      const bf16_t* rp = repv + rr * 68 + half * 32;
      float s = 0.f;
      #pragma unroll
      for (int c = 0; c < 4; c++) {
        bf16x8 vv = *(const bf16x8*)(rp + c * 8);
        #pragma unroll
        for (int e = 0; e < 8; e++) { float f = (float)vv[e]; s = fmaf(f, f, s); }
      }
      s += __shfl_xor(s, 1, 64);
      if (half == 0) {
        float sn0 = sqrtf(s);
        float vT = sqrtf(1.f + s);
        shc[rr] = __logf(vT + sn0) * frcp(fmaxf(sn0, 1e-8f));
      }
    }
    __syncthreads();
    // transposed scaled write: VTt[z][d][n]
    {
      int zz = (bm >> 10) * 8 + (blockIdx.y - 16);
      int nb = bm & 1023;
      int dbase = (t >> 4) * 4;
      int m = t & 15;
      bf16_t* dstz = vtt + (long)zz * 65536;
      #pragma unroll
      for (int p = 0; p < 4; p++) {
        int d = dbase + p;
        bf16x8 ov;
        #pragma unroll
        for (int e = 0; e < 8; e++) {
          int n = m * 8 + e;
          ov[e] = (bf16_t)((float)repv[n * 68 + d] * shc[n]);
        }
        *(bf16x8*)(dstz + (long)d * 1024 + nb + m * 8) = ov;
      }
    }
    return;
  }

  // ---- standard path: repack + coalesced store (+ stats) ----
  bf16_t* rep = (bf16_t*)smem;
  #pragma unroll
  for (int i = 0; i < 4; i++) {
    #pragma unroll
    for (int q = 0; q < 4; q++) {
      int r = wm + i * 16 + lh * 4 + q;
      #pragma unroll
      for (int j = 0; j < 2; j++) {
        float v = acc[i][j][q] + sh_t[r] * w0c[j];
        rep[r * 64 + wn + j * 16 + lm] = (bf16_t)(ACTF == 0 ? gelu_fast(v) : v);
      }
    }
  }
  __syncthreads();

  #pragma unroll
  for (int rd = 0; rd < 4; rd++) {
    int off = rd * 4096 + t * 16;
    int lr = off >> 7;
    int lc = (off & 127) >> 1;
    bf16x8 vv = *(const bf16x8*)(smem + off);
    *(bf16x8*)(Cg + (long)(bm + lr) * ldc + bn + lc) = vv;
  }

  if constexpr (STATS != 0) {
    int rr = t >> 1, half = t & 1;
    const bf16_t* rp = rep + rr * 64 + half * 32;
    float s = 0.f;
    #pragma unroll
    for (int c = 0; c < 4; c++) {
      bf16x8 vv = *(const bf16x8*)(rp + c * 8);
      #pragma unroll
      for (int e = 0; e < 8; e++) { float f = (float)vv[e]; s = fmaf(f, f, s); }
    }
    s += __shfl_xor(s, 1, 64);
    if (half == 0) {
      if constexpr (STATS == 2) {
        s0[(long)blockIdx.y * 2048 + bm + rr] = s;          // ||h_row||^2 partial
      } else {
        int bnh = blockIdx.y;                               // 0..15 here (q/k heads)
        int grow = bm + rr, bloc = grow >> 10, n = grow & 1023;
        if (bnh < 8) {
          int zz = bloc * 8 + bnh;
          float qT = sqrtf(1.f + s);
          s0[zz * 1024 + n] = qT;
          float beta = softplus_fast(beta_p[0]);
          float xq = fmaxf(qT, 1.001f);
          float sh_ = sqrtf(fmaxf(xq * xq - 1.f, 0.f));
          float rr0 = beta * frcp(sh_);
          s2[zz * 1024 + n] = sqrtf(fmaxf(1.f - rr0 * rr0, 0.f) + 1e-8f);
        } else {
          int zz = bloc * 8 + (bnh - 8);
          s1[zz * 1024 + n] = sqrtf(1.f + s);
        }
      }
    }
  }
}

// ---------------- fp32-out GEMM, BK=64, swizzled (64x64, 4 waves, K-range) ----------------
DEV void gemm_f32_body(
    const bf16_t* __restrict__ Ag, int lda,
    const bf16_t* __restrict__ Bg, int ldb,
    float* __restrict__ Cg, int ldc,
    int k0, int k1)
{
  __shared__ bf16_t As[64 * 64];
  __shared__ bf16_t Bs[64 * 64];
  const int t = threadIdx.x;
  const int wid = t >> 6, lane = t & 63;
  const int lm = lane & 15, lh = lane >> 4;
  const int bm = blockIdx.x * 64;
  const int bn = blockIdx.y * 64;
  const int wm = (wid >> 1) * 32;
  const int wn = (wid & 1) * 32;
  const int sb = (((lane & 7) ^ (lane >> 3)) << 4);
  const int r8 = lane >> 3;
  f32x4 acc[2][2] = {};

  for (int kk = k0; kk < k1; kk += 64) {
    __syncthreads();
    #pragma unroll
    for (int r = 0; r < 2; r++) {
      int chunk = wid * 2 + r;
      gl_lds16((const char*)(Ag + (long)(bm + chunk * 8 + r8) * lda + kk) + sb,
               (char*)As + chunk * 1024);
      gl_lds16((const char*)(Bg + (long)(bn + chunk * 8 + r8) * ldb + kk) + sb,
               (char*)Bs + chunk * 1024);
    }
    __syncthreads();
    #pragma unroll
    for (int k2 = 0; k2 < 2; k2++) {
      const int sl = (((k2 * 4 + lh) ^ (lm & 7)) << 3);
      bf16x8 af[2], bfr[2];
      #pragma unroll
      for (int i = 0; i < 2; i++) af[i] = *(const bf16x8*)&As[(wm + i * 16 + lm) * 64 + sl];
      #pragma unroll
      for (int j = 0; j < 2; j++) bfr[j] = *(const bf16x8*)&Bs[(wn + j * 16 + lm) * 64 + sl];
      #pragma unroll
      for (int i = 0; i < 2; i++)
        #pragma unroll
        for (int j = 0; j < 2; j++)
          acc[i][j] = MFMA16(af[i], bfr[j], acc[i][j]);
    }
  }

  #pragma unroll
  for (int i = 0; i < 2; i++) {
    #pragma unroll
    for (int q = 0; q < 4; q++) {
      long row = bm + wm + i * 16 + lh * 4 + q;
      #pragma unroll
      for (int j = 0; j < 2; j++)
        Cg[row * ldc + bn + wn + j * 16 + lm] = acc[i][j][q];
    }
  }
}

// ---- named wrappers ----
__global__ __launch_bounds__(256) void gemm_qkv(const bf16_t* A, int lda, const bf16_t* B, int ldb,
                                                bf16_t* C, int ldc, int K,
                                                const float* trow, const float* w0,
                                                float* qt, float* kt, float* Bi, const float* beta,
                                                bf16_t* vtt){
  gemm_rep_body<2, 1>(A, lda, B, ldb, C, ldc, K, trow, w0, qt, kt, Bi, beta, vtt);
}
__global__ __launch_bounds__(256) void gemm_f1(const bf16_t* A, int lda, const bf16_t* B, int ldb,
                                               bf16_t* C, int ldc, int K,
                                               const float* trow, const float* w0,
                                               float* th2p){
  gemm_rep_body<0, 2>(A, lda, B, ldb, C, ldc, K, trow, w0, th2p, nullptr, nullptr, nullptr, nullptr);
}
__global__ __launch_bounds__(256) void gemm_wo(const bf16_t* A, int lda, const bf16_t* B, int ldb,
                                               float* C, int ldc, int K){
  int k0 = blockIdx.z * (K >> 1);
  gemm_f32_body(A, lda, B, ldb, C + (long)blockIdx.z * 2048 * ldc, ldc, k0, k0 + (K >> 1));
}
__global__ __launch_bounds__(256) void gemm_f2(const bf16_t* A, int lda, const bf16_t* B, int ldb,
                                               float* C, int ldc, int K){
  int k0 = blockIdx.z * (K >> 2);
  gemm_f32_body(A, lda, B, ldb, C + (long)blockIdx.z * 2048 * ldc, ldc, k0, k0 + (K >> 2));
}

extern "C" void kernel_launch(void* const* d_in, const int* in_sizes, int n_in,
                              void* d_out, int out_size, void* d_ws, size_t ws_size,
                              hipStream_t stream) {
  const float* x    = (const float*)d_in[0];
  const float* Wq   = (const float*)d_in[1];
  const float* Wk   = (const float*)d_in[2];
  const float* Wv   = (const float*)d_in[3];
  const float* Wo   = (const float*)d_in[4];
  const float* W1   = (const float*)d_in[5];
  const float* W2   = (const float*)d_in[6];
  const float* g1   = (const float*)d_in[7];
  const float* b1   = (const float*)d_in[8];
  const float* g2   = (const float*)d_in[9];
  const float* b2   = (const float*)d_in[10];
  const float* temp = (const float*)d_in[11];
  const float* beta = (const float*)d_in[12];
  const float* tau  = (const float*)d_in[13];
  const float* lam  = (const float*)d_in[14];

  char* W = (char*)d_ws;
  bf16_t* Wqkvb = (bf16_t*)(W + 0);          // [1536][512]
  bf16_t* Wob   = (bf16_t*)(W + 1572864);    // [512][512]
  bf16_t* W1b   = (bf16_t*)(W + 2097152);    // [2048][512]
  bf16_t* W2b   = (bf16_t*)(W + 4194304);    // [512][2048]
  float*  wqkv0 = (float*) (W + 6291456);    // [1536]
  float*  wo0   = (float*) (W + 6297600);    // [512]
  float*  w10   = (float*) (W + 6299648);    // [2048]
  float*  w20   = (float*) (W + 6307840);    // [512]
  bf16_t* y1b   = (bf16_t*)(W + 6309888);    // [2048][512]
  float*  ty1   = (float*) (W + 8407040);    // [2048]
  bf16_t* qkvsb = (bf16_t*)(W + 8415232);    // [2048][1536]
  float*  qt    = (float*) (W + 14706688);   // [16384]
  float*  kt    = (float*) (W + 14772224);
  float*  Bi    = (float*) (W + 14837760);
  bf16_t* VTt   = (bf16_t*)(W + 14903296);   // [16][64][1024]
  float*  ch2   = (float*) (W + 17000448);   // [2048][8]
  bf16_t* attnb = (bf16_t*)(W + 17065984);   // [2048][512]
  float*  tmpA  = (float*) (W + 19163136);   // [2048][512] x4 partials (contiguous)
  float*  outs  = (float*) (W + 35940352);   // [2048][512]
  bf16_t* y2b   = (bf16_t*)(W + 40134656);   // [2048][512]
  float*  ty2   = (float*) (W + 42231808);   // [2048]
  bf16_t* hb    = (bf16_t*)(W + 42240000);   // [2048][2048]
  float*  th2p  = (float*) (W + 50628608);   // [32][2048]
  float*  tmpB  = tmpA + 1048576;
  float*  tmpC  = tmpA + 2097152;
  float*  tmpD  = tmpA + 3145728;

  // 0. LN1 + weight conversions (fused)
  prep<<<14354, 256, 0, stream>>>(x, g1, b1, Wq, Wk, Wv, Wo, W1, W2,
                                  y1b, ty1, Wqkvb, Wob, W1b, W2b, wqkv0, wo0, w10, w20);

  // 1. QKV projection (K=512) + rank-1 + q/k stats + fused v_tan/transpose
  //    -> qkvsb (q,k), qt, kt, Bi, VTt
  gemm_qkv<<<dim3(16,24,1),256,0,stream>>>(y1b, 512, Wqkvb, 512, qkvsb, 1536, 512,
                                           ty1, wqkv0, qt, kt, Bi, beta, VTt);

  // 2. fused attention + expmap merge -> attnb + ch2
  attn_fused<<<dim3(32,16,1),256,0,stream>>>(qkvsb, VTt, qt, kt, Bi, attnb, ch2, lam, tau, temp);

  // 3. Wo projection (K=512, split 2) -> tmpA/tmpB
  gemm_wo<<<dim3(32,8,2),256,0,stream>>>(attnb, 512, Wob, 512, tmpA, 512, 512);

  // 4. residual + rank-1(Wo time via ch2) + LN2 -> outs, y2b, ty2
  res_ln<<<2048, 256, 0, stream>>>(tmpA, tmpB, ch2, wo0, x, g2, b2, outs, y2b, ty2);

  // 5. FFN up (K=512) + rank-1 + GELU + ||h||^2 partials -> hb, th2p
  gemm_f1<<<dim3(16,32,1),256,0,stream>>>(y2b, 512, W1b, 512, hb, 2048, 512, ty2, w10, th2p);

  // 6. FFN down (K=2048, split 4) -> tmpA..D
  gemm_f2<<<dim3(32,8,4),256,0,stream>>>(hb, 2048, W2b, 2048, tmpA, 512, 2048);

  // 7. final: th from th2p + residual + rank-1(W2 time) + add_time -> d_out
  final_k<<<2048, 256, 0, stream>>>(tmpA, tmpB, tmpC, tmpD, th2p, w20, outs, (float*)d_out);
}

// Round 13
// 95.942 us; speedup vs baseline: 1.1001x; 1.0059x over previous
//
#include <hip/hip_runtime.h>
#include <math.h>

#define DEV static __device__ __forceinline__

typedef __bf16 bf16_t;
typedef __bf16 bf16x8 __attribute__((ext_vector_type(8)));
typedef float f32x4 __attribute__((ext_vector_type(4)));

#define MFMA16(a,b,c) __builtin_amdgcn_mfma_f32_16x16x32_bf16(a,b,c,0,0,0)

// ---------- fast transcendentals ----------
DEV float frcp(float x){ return __builtin_amdgcn_rcpf(x); }
DEV float softplus_fast(float x){
  return fmaxf(x, 0.f) + __logf(1.f + __expf(-fabsf(x)));
}
DEV float tanh_fast(float z){
  float e2 = __expf(2.f * z);
  return (e2 - 1.f) * frcp(e2 + 1.f);
}
DEV float gelu_fast(float v){
  float u = 0.7978845608028654f * fmaf(0.044715f * v, v * v, v);
  u = fminf(fmaxf(u, -15.f), 15.f);
  return 0.5f * v * (1.f + tanh_fast(u));
}

DEV void gl_lds16(const void* g, void* l) {
  __builtin_amdgcn_global_load_lds((const __attribute__((address_space(1))) void*)g,
                                   (__attribute__((address_space(3))) void*)l, 16, 0, 0);
}

DEV float waveReduceSum(float v){
  #pragma unroll
  for (int o = 32; o > 0; o >>= 1) v += __shfl_xor(v, o, 64);
  return v;
}
DEV float blockReduceSum(float v, float* sh){
  v = waveReduceSum(v);
  int w = threadIdx.x >> 6;
  int nw = blockDim.x >> 6;
  __syncthreads();
  if ((threadIdx.x & 63) == 0) sh[w] = v;
  __syncthreads();
  float r = sh[0];
  for (int i = 1; i < nw; i++) r += sh[i];
  return r;
}

// ---------------- prep: LN1 (blocks 0..2047) + weight conversions (rest) ----------------
__global__ __launch_bounds__(256) void prep(
    const float* __restrict__ xin,
    const float* __restrict__ g, const float* __restrict__ b,
    const float* __restrict__ Wq, const float* __restrict__ Wk,
    const float* __restrict__ Wv, const float* __restrict__ Wo,
    const float* __restrict__ W1, const float* __restrict__ W2,
    bf16_t* __restrict__ y, float* __restrict__ ty,
    bf16_t* __restrict__ Wqkvb, bf16_t* __restrict__ Wob,
    bf16_t* __restrict__ W1b, bf16_t* __restrict__ W2b,
    float* __restrict__ wqkv0, float* __restrict__ wo0,
    float* __restrict__ w10, float* __restrict__ w20)
{
  int t = threadIdx.x;
  if (blockIdx.x < 2048) {
    __shared__ float sh[8];
    int row = blockIdx.x;
    const float* xr = xin + (long)row * 513 + 1;
    float a0 = xr[t], a1 = xr[t + 256];
    float s  = blockReduceSum(a0 + a1, sh);
    float s2 = blockReduceSum(a0 * a0 + a1 * a1, sh);
    float mu = s * (1.f / 512.f);
    float var = s2 * (1.f / 512.f) - mu * mu;
    float inv = rsqrtf(var + 1e-5f);
    float y0 = (a0 - mu) * inv * g[t] + b[t];
    float y1v = (a1 - mu) * inv * g[t + 256] + b[t + 256];
    float q = blockReduceSum(y0 * y0 + y1v * y1v, sh);
    bf16_t* yr = y + (long)row * 512;
    yr[t] = (bf16_t)y0;
    yr[t + 256] = (bf16_t)y1v;
    if (t == 0) ty[row] = sqrtf(q + 1.f);
    return;
  }
  long i = (long)(blockIdx.x - 2048) * 256 + t;
  if (i < 786432) {                       // Wqkv spatial [1536][512]
    long r = i >> 9; int c = (int)(i & 511);
    const float* src = (r < 512) ? Wq + r * 513 : (r < 1024) ? Wk + (r - 512) * 513 : Wv + (r - 1024) * 513;
    Wqkvb[i] = (bf16_t)src[c + 1];
  } else if (i < 1048576) {               // Wo spatial [512][512]
    long j = i - 786432;
    long r = j >> 9; int c = (int)(j & 511);
    Wob[j] = (bf16_t)Wo[r * 513 + c + 1];
  } else if (i < 2097152) {               // W1 spatial [2048][512]
    long j = i - 1048576;
    long r = j >> 9; int c = (int)(j & 511);
    W1b[j] = (bf16_t)W1[r * 513 + c + 1];
  } else if (i < 3145728) {               // W2 spatial [512][2048]
    long j = i - 2097152;
    long r = j >> 11; int c = (int)(j & 2047);
    W2b[j] = (bf16_t)W2[r * 2049 + c + 1];
  } else if (i < 3150336) {               // time columns (fp32)
    int j = (int)(i - 3145728);
    if (j < 1536) {
      wqkv0[j] = (j < 512) ? Wq[(long)j * 513] : (j < 1024) ? Wk[(long)(j - 512) * 513] : Wv[(long)(j - 1024) * 513];
    } else if (j < 2048) wo0[j - 1536] = Wo[(long)(j - 1536) * 513];
    else if (j < 4096)  w10[j - 2048] = W1[(long)(j - 2048) * 513];
    else                w20[j - 4096] = W2[(long)(j - 4096) * 2049];
  }
}

// ---------------- residual + rank-1(Wo time) + LN2 -> outs, y2b, ty2 ----------------
__global__ __launch_bounds__(256) void res_ln(
    const float* __restrict__ woA, const float* __restrict__ woB,
    const float* __restrict__ ch2, const float* __restrict__ wo0,
    const float* __restrict__ xin,
    const float* __restrict__ g, const float* __restrict__ b,
    float* __restrict__ outs,
    bf16_t* __restrict__ y, float* __restrict__ ty)
{
  __shared__ float sh[8];
  int row = blockIdx.x;
  int t = threadIdx.x;
  const float* c = ch2 + (long)row * 8;
  float cs = ((c[0] + c[1]) + (c[2] + c[3])) + ((c[4] + c[5]) + (c[6] + c[7]));
  float tattn = sqrtf(fmaxf(cs - 7.f, 1e-8f));
  long i0 = (long)row * 512 + t, i1 = i0 + 256;
  float a0 = woA[i0] + woB[i0] + tattn * wo0[t]       + xin[(long)row * 513 + 1 + t];
  float a1 = woA[i1] + woB[i1] + tattn * wo0[t + 256] + xin[(long)row * 513 + 1 + t + 256];
  outs[i0] = a0;
  outs[i1] = a1;
  float s  = blockReduceSum(a0 + a1, sh);
  float s2 = blockReduceSum(a0 * a0 + a1 * a1, sh);
  float mu = s * (1.f / 512.f);
  float var = s2 * (1.f / 512.f) - mu * mu;
  float inv = rsqrtf(var + 1e-5f);
  float y0 = (a0 - mu) * inv * g[t] + b[t];
  float y1v = (a1 - mu) * inv * g[t + 256] + b[t + 256];
  float q = blockReduceSum(y0 * y0 + y1v * y1v, sh);
  bf16_t* yr = y + (long)row * 512;
  yr[t] = (bf16_t)y0;
  yr[t + 256] = (bf16_t)y1v;
  if (t == 0) ty[row] = sqrtf(q + 1.f);
}

// ---------------- final: th2p-sum + residual(4 partials) + rank-1 + add_time ----------------
__global__ __launch_bounds__(256) void final_k(
    const float* __restrict__ hA, const float* __restrict__ hB,
    const float* __restrict__ hC, const float* __restrict__ hD,
    const float* __restrict__ th2p, const float* __restrict__ w20,
    const float* __restrict__ outs,
    float* __restrict__ out)
{
  __shared__ float sh[8];
  int row = blockIdx.x;
  int t = threadIdx.x;
  float p = (t < 32) ? th2p[(long)t * 2048 + row] : 0.f;
  float hn = blockReduceSum(p, sh);
  float th = sqrtf(hn + 1.f);
  long i0 = (long)row * 512 + t, i1 = i0 + 256;
  float o0 = (hA[i0] + hB[i0]) + (hC[i0] + hD[i0]) + th * w20[t]       + outs[i0];
  float o1 = (hA[i1] + hB[i1]) + (hC[i1] + hD[i1]) + th * w20[t + 256] + outs[i1];
  float q = blockReduceSum(o0 * o0 + o1 * o1, sh);
  float* yr = out + (long)row * 513;
  yr[1 + t] = o0;
  yr[1 + t + 256] = o1;
  if (t == 0) yr[0] = sqrtf(q + 1.f);
}

// ---------------- fused attention + expmap merge (compact Q/K, XOR-swizzled LDS) ----------------
__global__ __launch_bounds__(256) void attn_fused(
    const bf16_t* __restrict__ Qb,      // [16][1024][64]
    const bf16_t* __restrict__ Kb,      // [16][1024][64]
    const bf16_t* __restrict__ VTt,     // [16][64][1024]
    const float* __restrict__ qt, const float* __restrict__ kt,
    const float* __restrict__ Bi,
    bf16_t* __restrict__ attnb,         // [2048][512]
    float* __restrict__ ch2,            // [2048][8]
    const float* __restrict__ lam_p, const float* __restrict__ tau_p,
    const float* __restrict__ temp_p)
{
  __shared__ bf16_t Ks[64 * 64];
  __shared__ bf16_t Vs[64 * 64];
  __shared__ bf16_t Ps[32 * 72];
  __shared__ float ot[32 * 65];
  __shared__ float sh_qt[32], sh_Bc[32], sh_kt[64], rs[32];

  const int t = threadIdx.x;
  const int w = t >> 6;
  const int lane = t & 63;
  const int lm = lane & 15, lh = lane >> 4;
  const int z = blockIdx.y, b = z >> 3, h = z & 7;
  const int n0 = blockIdx.x * 32;
  const int sb = (((lane & 7) ^ (lane >> 3)) << 4);
  const int r8 = lane >> 3;

  float lam = softplus_fast(lam_p[0]);
  float tau = softplus_fast(tau_p[0]);
  float invT = frcp(temp_p[0]);
  float A1 = -lam * invT, A2 = -tau * invT;
  float A2h = 0.5f * A2, K0 = A2 * 0.048750465f;

  if (t < 32) {
    sh_qt[t] = qt[z * 1024 + n0 + t];
    sh_Bc[t] = Bi[z * 1024 + n0 + t] - 0.1f;
    rs[t] = 0.f;
  }

  // stage Q (32x64 contiguous, swizzled) then preload frags
  const bf16_t* qbase = Qb + (long)z * 65536 + (long)n0 * 64;
  gl_lds16((const char*)(qbase + (long)(w * 8 + r8) * 64) + sb, (char*)Ks + w * 1024);
  __syncthreads();
  bf16x8 qf[2][2];
  #pragma unroll
  for (int i = 0; i < 2; i++)
    #pragma unroll
    for (int kk = 0; kk < 2; kk++)
      qf[i][kk] = *(const bf16x8*)&Ks[(i * 16 + lm) * 64 + (((kk * 4 + lh) ^ (lm & 7)) << 3)];

  f32x4 oacc[2] = {};
  float racc[2][4] = {};

  const bf16_t* kbase = Kb + (long)z * 65536;
  const bf16_t* vbase = VTt + (long)z * 64 * 1024;
  const int sl0 = ((lh) ^ (lm & 7)) << 3;
  const int sl1 = ((4 + lh) ^ (lm & 7)) << 3;

  for (int kv = 0; kv < 16; kv++) {
    __syncthreads();
    {
      const bf16_t* kb = kbase + (long)(kv * 64) * 64;
      gl_lds16((const char*)(kb + (long)(w * 16 + r8) * 64) + sb,     (char*)Ks + (w * 2) * 1024);
      gl_lds16((const char*)(kb + (long)(w * 16 + 8 + r8) * 64) + sb, (char*)Ks + (w * 2 + 1) * 1024);
      const bf16_t* vb = vbase + kv * 64;
      gl_lds16((const char*)(vb + (long)(w * 16 + r8) * 1024) + sb,     (char*)Vs + (w * 2) * 1024);
      gl_lds16((const char*)(vb + (long)(w * 16 + 8 + r8) * 1024) + sb, (char*)Vs + (w * 2 + 1) * 1024);
    }
    if (t < 64) sh_kt[t] = kt[z * 1024 + kv * 64 + t];
    __syncthreads();

    f32x4 sacc[2] = {};
    bf16x8 kf0 = *(const bf16x8*)&Ks[(w * 16 + lm) * 64 + sl0];
    bf16x8 kf1 = *(const bf16x8*)&Ks[(w * 16 + lm) * 64 + sl1];
    sacc[0] = MFMA16(qf[0][0], kf0, sacc[0]);
    sacc[0] = MFMA16(qf[0][1], kf1, sacc[0]);
    sacc[1] = MFMA16(qf[1][0], kf0, sacc[1]);
    sacc[1] = MFMA16(qf[1][1], kf1, sacc[1]);

    float ktv = sh_kt[w * 16 + lm];
    #pragma unroll
    for (int i = 0; i < 2; i++) {
      #pragma unroll
      for (int q = 0; q < 4; q++) {
        int r = i * 16 + lh * 4 + q;
        float qtv = sh_qt[r], Bc = sh_Bc[r];
        float nOQ = fmaf(qtv, qtv, -1.f);
        float inner = fmaf(-qtv, ktv, sacc[i][q]);
        float nQK = fmaxf(fmaf(inner, inner, -1.f), 0.f);
        float ri = __builtin_amdgcn_rsqf(fmaf(nQK, nOQ, 2.5e-5f));
        float zr = fmaf(inner, qtv, ktv) * ri;
        float Zc = fminf(fmaxf(-zr, -1.f), 1.f);
        float xx = fmaxf(-inner, 1.001f);
        float u = fmaf(__log2f(xx), 0.01732868f, 0.01732868f);
        float p = fminf(u * u, 0.09f);
        float H = p * fmaf(p, -6.584f, 3.5556f);
        float a = Zc + Bc;
        float a2 = a * a;
        float lc = a2 * fmaf(a2, fmaf(a2, 0.00034722f, -0.0052083f), 0.125f);
        float lgt = fmaf(A1, H, fmaf(A2, lc, fmaf(A2h, a, K0)));
        float e = __expf(lgt);
        Ps[r * 72 + w * 16 + lm] = (bf16_t)e;
        racc[i][q] += e;
      }
    }
    __syncthreads();

    bf16x8 va0 = *(const bf16x8*)&Vs[(w * 16 + lm) * 64 + sl0];
    bf16x8 va1 = *(const bf16x8*)&Vs[(w * 16 + lm) * 64 + sl1];
    bf16x8 pb00 = *(const bf16x8*)&Ps[lm * 72 + lh * 8];
    bf16x8 pb01 = *(const bf16x8*)&Ps[lm * 72 + 32 + lh * 8];
    bf16x8 pb10 = *(const bf16x8*)&Ps[(16 + lm) * 72 + lh * 8];
    bf16x8 pb11 = *(const bf16x8*)&Ps[(16 + lm) * 72 + 32 + lh * 8];
    oacc[0] = MFMA16(va0, pb00, oacc[0]);
    oacc[0] = MFMA16(va1, pb01, oacc[0]);
    oacc[1] = MFMA16(va0, pb10, oacc[1]);
    oacc[1] = MFMA16(va1, pb11, oacc[1]);
  }

  #pragma unroll
  for (int i = 0; i < 2; i++)
    #pragma unroll
    for (int q = 0; q < 4; q++) {
      float v = racc[i][q];
      v += __shfl_xor(v, 1, 64);
      v += __shfl_xor(v, 2, 64);
      v += __shfl_xor(v, 4, 64);
      v += __shfl_xor(v, 8, 64);
      if (lm == 0) atomicAdd(&rs[i * 16 + lh * 4 + q], v);
    }

  #pragma unroll
  for (int j = 0; j < 2; j++)
    #pragma unroll
    for (int q = 0; q < 4; q++)
      ot[(j * 16 + lm) * 65 + w * 16 + lh * 4 + q] = oacc[j][q];
  __syncthreads();

  int r = t >> 3, c0 = (t & 7) * 8;
  float inv = frcp(rs[r] * (1.f + 1e-8f));
  float v[8];
  float ss = 0.f;
  #pragma unroll
  for (int e = 0; e < 8; e++) {
    v[e] = ot[r * 65 + c0 + e] * inv;
    ss = fmaf(v[e], v[e], ss);
  }
  ss += __shfl_xor(ss, 1, 64);
  ss += __shfl_xor(ss, 2, 64);
  ss += __shfl_xor(ss, 4, 64);
  float nn = fmaxf(sqrtf(ss), 1e-8f);
  float e_ = __expf(nn), ei = frcp(e_);
  float coef = 0.5f * (e_ - ei) * frcp(nn);
  bf16x8 ov;
  #pragma unroll
  for (int e = 0; e < 8; e++) ov[e] = (bf16_t)(coef * v[e]);
  *(bf16x8*)(attnb + (long)(b * 1024 + n0 + r) * 512 + h * 64 + c0) = ov;
  if (c0 == 0) {
    float ch = 0.5f * (e_ + ei);
    ch2[(long)(b * 1024 + n0 + r) * 8 + h] = ch * ch;
  }
}

// ============ bf16-out GEMM, 128x64 tiles, BK=64, swizzled, rank-1 + stats + v_tan fusion ============
// ACTF: 0 = GELU | 2 = plain.  STATS: 0 none | 1 qkv (q/k compact + stats, v->VTt) | 2 ||.||^2 (F1)
template<int ACTF, int STATS>
DEV void gemm_rep_body(
    const bf16_t* __restrict__ Ag, int lda,
    const bf16_t* __restrict__ Bg, int ldb,
    bf16_t* __restrict__ Cg, int ldc, int K,
    const float* __restrict__ trow, const float* __restrict__ w0,
    float* __restrict__ s0, float* __restrict__ s1, float* __restrict__ s2,
    const float* __restrict__ beta_p,
    bf16_t* __restrict__ vtt, bf16_t* __restrict__ qb, bf16_t* __restrict__ kb)
{
  __shared__ char smem[24576];          // k-loop: As 16K | Bs 8K ; epilogue reuse
  __shared__ float sh_t[128];
  __shared__ float shc[128];
  bf16_t* As = (bf16_t*)smem;
  bf16_t* Bs = (bf16_t*)(smem + 16384);
  const int t = threadIdx.x;
  const int wid = t >> 6, lane = t & 63;
  const int lm = lane & 15, lh = lane >> 4;
  const int bm = blockIdx.x * 128;
  const int bn = blockIdx.y * 64;
  const int wm = (wid >> 1) * 64;
  const int wn = (wid & 1) * 32;
  const int sb = (((lane & 7) ^ (lane >> 3)) << 4);
  const int r8 = lane >> 3;
  f32x4 acc[4][2] = {};

  if (t < 128) sh_t[t] = trow[bm + t];
  float w0c[2] = { w0[bn + wn + lm], w0[bn + wn + 16 + lm] };

  for (int kk = 0; kk < K; kk += 64) {
    __syncthreads();
    #pragma unroll
    for (int r = 0; r < 4; r++) {
      int chunk = wid * 4 + r;
      gl_lds16((const char*)(Ag + (long)(bm + chunk * 8 + r8) * lda + kk) + sb,
               smem + chunk * 1024);
    }
    #pragma unroll
    for (int r = 0; r < 2; r++) {
      int chunk = wid * 2 + r;
      gl_lds16((const char*)(Bg + (long)(bn + chunk * 8 + r8) * ldb + kk) + sb,
               smem + 16384 + chunk * 1024);
    }
    __syncthreads();
    #pragma unroll
    for (int k2 = 0; k2 < 2; k2++) {
      const int sl = (((k2 * 4 + lh) ^ (lm & 7)) << 3);
      bf16x8 af[4], bfr[2];
      #pragma unroll
      for (int i = 0; i < 4; i++) af[i] = *(const bf16x8*)&As[(wm + i * 16 + lm) * 64 + sl];
      #pragma unroll
      for (int j = 0; j < 2; j++) bfr[j] = *(const bf16x8*)&Bs[(wn + j * 16 + lm) * 64 + sl];
      #pragma unroll
      for (int i = 0; i < 4; i++)
        #pragma unroll
        for (int j = 0; j < 2; j++)
          acc[i][j] = MFMA16(af[i], bfr[j], acc[i][j]);
    }
  }

  __syncthreads();                       // staging dead

  if (STATS == 1 && blockIdx.y >= 16) {
    // ---- v-tile path: v_tan + transpose fused ----
    bf16_t* repv = (bf16_t*)smem;        // [128][68] padded
    #pragma unroll
    for (int i = 0; i < 4; i++) {
      #pragma unroll
      for (int q = 0; q < 4; q++) {
        int r = wm + i * 16 + lh * 4 + q;
        #pragma unroll
        for (int j = 0; j < 2; j++) {
          float v = acc[i][j][q] + sh_t[r] * w0c[j];
          repv[r * 68 + wn + j * 16 + lm] = (bf16_t)v;
        }
      }
    }
    __syncthreads();
    {
      int rr = t >> 1, half = t & 1;
      const bf16_t* rp = repv + rr * 68 + half * 32;
      float s = 0.f;
      #pragma unroll
      for (int c = 0; c < 4; c++) {
        bf16x8 vv = *(const bf16x8*)(rp + c * 8);
        #pragma unroll
        for (int e = 0; e < 8; e++) { float f = (float)vv[e]; s = fmaf(f, f, s); }
      }
      s += __shfl_xor(s, 1, 64);
      if (half == 0) {
        float sn0 = sqrtf(s);
        float vT = sqrtf(1.f + s);
        shc[rr] = __logf(vT + sn0) * frcp(fmaxf(sn0, 1e-8f));
      }
    }
    __syncthreads();
    {
      int zz = (bm >> 10) * 8 + (blockIdx.y - 16);
      int nb = bm & 1023;
      int dbase = (t >> 4) * 4;
      int m = t & 15;
      bf16_t* dstz = vtt + (long)zz * 65536;
      #pragma unroll
      for (int p = 0; p < 4; p++) {
        int d = dbase + p;
        bf16x8 ov;
        #pragma unroll
        for (int e = 0; e < 8; e++) {
          int n = m * 8 + e;
          ov[e] = (bf16_t)((float)repv[n * 68 + d] * shc[n]);
        }
        *(bf16x8*)(dstz + (long)d * 1024 + nb + m * 8) = ov;
      }
    }
    return;
  }

  // ---- standard path: repack + coalesced store (+ stats) ----
  bf16_t* rep = (bf16_t*)smem;
  #pragma unroll
  for (int i = 0; i < 4; i++) {
    #pragma unroll
    for (int q = 0; q < 4; q++) {
      int r = wm + i * 16 + lh * 4 + q;
      #pragma unroll
      for (int j = 0; j < 2; j++) {
        float v = acc[i][j][q] + sh_t[r] * w0c[j];
        rep[r * 64 + wn + j * 16 + lm] = (bf16_t)(ACTF == 0 ? gelu_fast(v) : v);
      }
    }
  }
  __syncthreads();

  if constexpr (STATS == 1) {
    // q/k tiles: write compact per-head [z][n][64]
    bf16_t* qkdst = (blockIdx.y < 8) ? qb : kb;
    int hh = blockIdx.y & 7;
    #pragma unroll
    for (int rd = 0; rd < 4; rd++) {
      int off = rd * 4096 + t * 16;
      int lr = off >> 7;
      int lc = (off & 127) >> 1;
      int grow = bm + lr;
      int bloc = grow >> 10, n = grow & 1023;
      bf16x8 vv = *(const bf16x8*)(smem + off);
      *(bf16x8*)(qkdst + ((long)(bloc * 8 + hh) * 1024 + n) * 64 + lc) = vv;
    }
  } else {
    #pragma unroll
    for (int rd = 0; rd < 4; rd++) {
      int off = rd * 4096 + t * 16;
      int lr = off >> 7;
      int lc = (off & 127) >> 1;
      bf16x8 vv = *(const bf16x8*)(smem + off);
      *(bf16x8*)(Cg + (long)(bm + lr) * ldc + bn + lc) = vv;
    }
  }

  if constexpr (STATS != 0) {
    int rr = t >> 1, half = t & 1;
    const bf16_t* rp = rep + rr * 64 + half * 32;
    float s = 0.f;
    #pragma unroll
    for (int c = 0; c < 4; c++) {
      bf16x8 vv = *(const bf16x8*)(rp + c * 8);
      #pragma unroll
      for (int e = 0; e < 8; e++) { float f = (float)vv[e]; s = fmaf(f, f, s); }
    }
    s += __shfl_xor(s, 1, 64);
    if (half == 0) {
      if constexpr (STATS == 2) {
        s0[(long)blockIdx.y * 2048 + bm + rr] = s;          // ||h_row||^2 partial
      } else {
        int bnh = blockIdx.y;                               // 0..15 here (q/k heads)
        int grow = bm + rr, bloc = grow >> 10, n = grow & 1023;
        if (bnh < 8) {
          int zz = bloc * 8 + bnh;
          float qT = sqrtf(1.f + s);
          s0[zz * 1024 + n] = qT;
          float beta = softplus_fast(beta_p[0]);
          float xq = fmaxf(qT, 1.001f);
          float sh_ = sqrtf(fmaxf(xq * xq - 1.f, 0.f));
          float rr0 = beta * frcp(sh_);
          s2[zz * 1024 + n] = sqrtf(fmaxf(1.f - rr0 * rr0, 0.f) + 1e-8f);
        } else {
          int zz = bloc * 8 + (bnh - 8);
          s1[zz * 1024 + n] = sqrtf(1.f + s);
        }
      }
    }
  }
}

// ---------------- fp32-out GEMM, BK=64, swizzled (64x64, 4 waves, K-range) ----------------
DEV void gemm_f32_body(
    const bf16_t* __restrict__ Ag, int lda,
    const bf16_t* __restrict__ Bg, int ldb,
    float* __restrict__ Cg, int ldc,
    int k0, int k1)
{
  __shared__ bf16_t As[64 * 64];
  __shared__ bf16_t Bs[64 * 64];
  const int t = threadIdx.x;
  const int wid = t >> 6, lane = t & 63;
  const int lm = lane & 15, lh = lane >> 4;
  const int bm = blockIdx.x * 64;
  const int bn = blockIdx.y * 64;
  const int wm = (wid >> 1) * 32;
  const int wn = (wid & 1) * 32;
  const int sb = (((lane & 7) ^ (lane >> 3)) << 4);
  const int r8 = lane >> 3;
  f32x4 acc[2][2] = {};

  for (int kk = k0; kk < k1; kk += 64) {
    __syncthreads();
    #pragma unroll
    for (int r = 0; r < 2; r++) {
      int chunk = wid * 2 + r;
      gl_lds16((const char*)(Ag + (long)(bm + chunk * 8 + r8) * lda + kk) + sb,
               (char*)As + chunk * 1024);
      gl_lds16((const char*)(Bg + (long)(bn + chunk * 8 + r8) * ldb + kk) + sb,
               (char*)Bs + chunk * 1024);
    }
    __syncthreads();
    #pragma unroll
    for (int k2 = 0; k2 < 2; k2++) {
      const int sl = (((k2 * 4 + lh) ^ (lm & 7)) << 3);
      bf16x8 af[2], bfr[2];
      #pragma unroll
      for (int i = 0; i < 2; i++) af[i] = *(const bf16x8*)&As[(wm + i * 16 + lm) * 64 + sl];
      #pragma unroll
      for (int j = 0; j < 2; j++) bfr[j] = *(const bf16x8*)&Bs[(wn + j * 16 + lm) * 64 + sl];
      #pragma unroll
      for (int i = 0; i < 2; i++)
        #pragma unroll
        for (int j = 0; j < 2; j++)
          acc[i][j] = MFMA16(af[i], bfr[j], acc[i][j]);
    }
  }

  #pragma unroll
  for (int i = 0; i < 2; i++) {
    #pragma unroll
    for (int q = 0; q < 4; q++) {
      long row = bm + wm + i * 16 + lh * 4 + q;
      #pragma unroll
      for (int j = 0; j < 2; j++)
        Cg[row * ldc + bn + wn + j * 16 + lm] = acc[i][j][q];
    }
  }
}

// ---- named wrappers ----
__global__ __launch_bounds__(256) void gemm_qkv(const bf16_t* A, int lda, const bf16_t* B, int ldb,
                                                int K,
                                                const float* trow, const float* w0,
                                                float* qt, float* kt, float* Bi, const float* beta,
                                                bf16_t* vtt, bf16_t* qb, bf16_t* kb){
  gemm_rep_body<2, 1>(A, lda, B, ldb, nullptr, 0, K, trow, w0, qt, kt, Bi, beta, vtt, qb, kb);
}
__global__ __launch_bounds__(256) void gemm_f1(const bf16_t* A, int lda, const bf16_t* B, int ldb,
                                               bf16_t* C, int ldc, int K,
                                               const float* trow, const float* w0,
                                               float* th2p){
  gemm_rep_body<0, 2>(A, lda, B, ldb, C, ldc, K, trow, w0, th2p, nullptr, nullptr, nullptr,
                      nullptr, nullptr, nullptr);
}
__global__ __launch_bounds__(256) void gemm_wo(const bf16_t* A, int lda, const bf16_t* B, int ldb,
                                               float* C, int ldc, int K){
  int k0 = blockIdx.z * (K >> 1);
  gemm_f32_body(A, lda, B, ldb, C + (long)blockIdx.z * 2048 * ldc, ldc, k0, k0 + (K >> 1));
}
__global__ __launch_bounds__(256) void gemm_f2(const bf16_t* A, int lda, const bf16_t* B, int ldb,
                                               float* C, int ldc, int K){
  int k0 = blockIdx.z * (K >> 2);
  gemm_f32_body(A, lda, B, ldb, C + (long)blockIdx.z * 2048 * ldc, ldc, k0, k0 + (K >> 2));
}

extern "C" void kernel_launch(void* const* d_in, const int* in_sizes, int n_in,
                              void* d_out, int out_size, void* d_ws, size_t ws_size,
                              hipStream_t stream) {
  const float* x    = (const float*)d_in[0];
  const float* Wq   = (const float*)d_in[1];
  const float* Wk   = (const float*)d_in[2];
  const float* Wv   = (const float*)d_in[3];
  const float* Wo   = (const float*)d_in[4];
  const float* W1   = (const float*)d_in[5];
  const float* W2   = (const float*)d_in[6];
  const float* g1   = (const float*)d_in[7];
  const float* b1   = (const float*)d_in[8];
  const float* g2   = (const float*)d_in[9];
  const float* b2   = (const float*)d_in[10];
  const float* temp = (const float*)d_in[11];
  const float* beta = (const float*)d_in[12];
  const float* tau  = (const float*)d_in[13];
  const float* lam  = (const float*)d_in[14];

  char* W = (char*)d_ws;
  bf16_t* Wqkvb = (bf16_t*)(W + 0);          // [1536][512]
  bf16_t* Wob   = (bf16_t*)(W + 1572864);    // [512][512]
  bf16_t* W1b   = (bf16_t*)(W + 2097152);    // [2048][512]
  bf16_t* W2b   = (bf16_t*)(W + 4194304);    // [512][2048]
  float*  wqkv0 = (float*) (W + 6291456);    // [1536]
  float*  wo0   = (float*) (W + 6297600);    // [512]
  float*  w10   = (float*) (W + 6299648);    // [2048]
  float*  w20   = (float*) (W + 6307840);    // [512]
  bf16_t* y1b   = (bf16_t*)(W + 6309888);    // [2048][512]
  float*  ty1   = (float*) (W + 8407040);    // [2048]
  bf16_t* Qb    = (bf16_t*)(W + 8415232);    // [16][1024][64]
  bf16_t* Kb    = (bf16_t*)(W + 10512384);   // [16][1024][64]
  float*  qt    = (float*) (W + 12609536);   // [16384]
  float*  kt    = (float*) (W + 12675072);
  float*  Bi    = (float*) (W + 12740608);
  bf16_t* VTt   = (bf16_t*)(W + 12806144);   // [16][64][1024]
  float*  ch2   = (float*) (W + 14903296);   // [2048][8]
  bf16_t* attnb = (bf16_t*)(W + 14968832);   // [2048][512]
  float*  tmpA  = (float*) (W + 17065984);   // [2048][512] x4 partials (contiguous)
  float*  outs  = (float*) (W + 33843200);   // [2048][512]
  bf16_t* y2b   = (bf16_t*)(W + 38037504);   // [2048][512]
  float*  ty2   = (float*) (W + 40134656);   // [2048]
  bf16_t* hb    = (bf16_t*)(W + 40142848);   // [2048][2048]
  float*  th2p  = (float*) (W + 48531456);   // [32][2048]  (end ~48.8 MB)
  float*  tmpB  = tmpA + 1048576;
  float*  tmpC  = tmpA + 2097152;
  float*  tmpD  = tmpA + 3145728;

  // 0. LN1 + weight conversions (fused)
  prep<<<14354, 256, 0, stream>>>(x, g1, b1, Wq, Wk, Wv, Wo, W1, W2,
                                  y1b, ty1, Wqkvb, Wob, W1b, W2b, wqkv0, wo0, w10, w20);

  // 1. QKV projection (K=512) + rank-1 + q/k compact + stats + fused v_tan/transpose
  //    -> Qb, Kb, qt, kt, Bi, VTt
  gemm_qkv<<<dim3(16,24,1),256,0,stream>>>(y1b, 512, Wqkvb, 512, 512,
                                           ty1, wqkv0, qt, kt, Bi, beta, VTt, Qb, Kb);

  // 2. fused attention + expmap merge -> attnb + ch2
  attn_fused<<<dim3(32,16,1),256,0,stream>>>(Qb, Kb, VTt, qt, kt, Bi, attnb, ch2, lam, tau, temp);

  // 3. Wo projection (K=512, split 2) -> tmpA/tmpB
  gemm_wo<<<dim3(32,8,2),256,0,stream>>>(attnb, 512, Wob, 512, tmpA, 512, 512);

  // 4. residual + rank-1(Wo time via ch2) + LN2 -> outs, y2b, ty2
  res_ln<<<2048, 256, 0, stream>>>(tmpA, tmpB, ch2, wo0, x, g2, b2, outs, y2b, ty2);

  // 5. FFN up (K=512) + rank-1 + GELU + ||h||^2 partials -> hb, th2p
  gemm_f1<<<dim3(16,32,1),256,0,stream>>>(y2b, 512, W1b, 512, hb, 2048, 512, ty2, w10, th2p);

  // 6. FFN down (K=2048, split 4) -> tmpA..D
  gemm_f2<<<dim3(32,8,4),256,0,stream>>>(hb, 2048, W2b, 2048, tmpA, 512, 2048);

  // 7. final: th from th2p + residual + rank-1(W2 time) + add_time -> d_out
  final_k<<<2048, 256, 0, stream>>>(tmpA, tmpB, tmpC, tmpD, th2p, w20, outs, (float*)d_out);
}